// Round 1
// baseline (2261.790 us; speedup 1.0000x reference)
//
#include <hip/hip_runtime.h>
#include <math.h>

// GAT 2-layer, N=50000, E=800000 (+N self loops), IN=128, HID=32, HEADS=4, OUT=32
#define NN   50000
#define EE   800000
#define ETOT 850000          // EE + NN
#define NEG  0.2f

// -------- workspace layout (float offsets) --------
// zero-initialized region (one contiguous memset):
#define O_OUT1   0           // 6,400,000  layer-1 aggregation output [N][128]
#define O_DEN1   6400000     //   200,000  softmax denominators layer1 [N][4]
#define O_DEN2   6600000     //    50,000  softmax denominators layer2 [N]
#define O_ASRC2  6650000     //    50,000  per-node src logits layer2
#define O_ADST2  6700000     //    50,000  per-node dst logits layer2
#define O_EASUM  6750000     //         4  edge_attr sum (scalar)
#define ZERO_FLOATS 6750004
// non-zeroed:
#define O_COEF   6750004     //         8  coef1[4], coef2 at [4]
#define O_XL     6750012     // 6,400,000  layer-1 features [N][128]
#define O_ASRC1  13150012    //   200,000  per-node src logits layer1 [N][4]
#define O_ADST1  13350012    //   200,000  per-node dst logits layer1 [N][4]
#define O_HL     13550012    // 1,600,000  layer-2 features [N][32]
#define O_EX1    15150012    // 3,400,000  exp(alpha1) per edge [Etot][4]
#define O_EX2    18550012    //   850,000  exp(alpha2) per edge [Etot]
#define WS_FLOATS 19400012   // ~77.6 MB

// -------------------- edge_attr mean (sum) --------------------
__global__ void k_ea_reduce(const float* __restrict__ ea, float* __restrict__ easum) {
  __shared__ float red[4];
  float s = 0.f;
  int stride = gridDim.x * blockDim.x;
  for (int i = blockIdx.x * blockDim.x + threadIdx.x; i < EE; i += stride)
    s += ea[i];
  #pragma unroll
  for (int o = 32; o > 0; o >>= 1) s += __shfl_down(s, o, 64);
  if ((threadIdx.x & 63) == 0) red[threadIdx.x >> 6] = s;
  __syncthreads();
  if (threadIdx.x == 0) {
    atomicAdd(easum, red[0] + red[1] + red[2] + red[3]);
  }
}

// -------------------- edge-coef precompute --------------------
// coef1[h] = sum_c lin1_edge_w[h*32+c] * att1_edge[h*32+c];  coef2 = sum_c lin2_edge_w[c]*att2_edge[c]
__global__ void k_coef(const float* __restrict__ lew1, const float* __restrict__ ae1,
                       const float* __restrict__ lew2, const float* __restrict__ ae2,
                       float* __restrict__ coef) {
  int t = threadIdx.x; // 128 threads
  float p = lew1[t] * ae1[t];
  #pragma unroll
  for (int o = 16; o > 0; o >>= 1) p += __shfl_down(p, o, 32);
  if ((t & 31) == 0) coef[t >> 5] = p;
  if (t < 32) {
    float q = lew2[t] * ae2[t];
    #pragma unroll
    for (int o = 16; o > 0; o >>= 1) q += __shfl_down(q, o, 32);
    if (t == 0) coef[4] = q;
  }
}

// -------------------- layer-1 GEMM: xl = x @ W1, plus per-node logits --------------------
// block = 256 = 4 waves; block handles 64 nodes; wave w computes head w's 32 channels.
// x tile staged transposed in LDS (stride 65 -> conflict-free ds_read_b32, lane=node).
__global__ __launch_bounds__(256) void k_lin1(
    const float* __restrict__ x, const float* __restrict__ W,
    const float* __restrict__ att_src, const float* __restrict__ att_dst,
    float* __restrict__ xl, float* __restrict__ asrc, float* __restrict__ adst) {
  __shared__ float xT[128][65];
  const int n0 = blockIdx.x * 64;
  const int t = threadIdx.x;
  #pragma unroll
  for (int i = 0; i < 8; ++i) {
    int f = t + 256 * i;          // float4 index within 64x128 tile
    int n = f >> 5;
    int k4 = (f & 31) << 2;
    int nn = n0 + n;
    float4 v = make_float4(0.f, 0.f, 0.f, 0.f);
    if (nn < NN) v = *(const float4*)(x + (size_t)nn * 128 + k4);
    xT[k4 + 0][n] = v.x;
    xT[k4 + 1][n] = v.y;
    xT[k4 + 2][n] = v.z;
    xT[k4 + 3][n] = v.w;
  }
  __syncthreads();
  const int w = t >> 6;       // head / wave id
  const int lane = t & 63;    // node within tile
  const int n = n0 + lane;
  float acc[32];
  #pragma unroll
  for (int j = 0; j < 32; ++j) acc[j] = 0.f;
  for (int k = 0; k < 128; ++k) {
    float xv = xT[k][lane];
    const float4* Wr = (const float4*)(W + k * 128 + w * 32);  // wave-uniform
    #pragma unroll
    for (int j4 = 0; j4 < 8; ++j4) {
      float4 wv = Wr[j4];
      acc[j4 * 4 + 0] += xv * wv.x;
      acc[j4 * 4 + 1] += xv * wv.y;
      acc[j4 * 4 + 2] += xv * wv.z;
      acc[j4 * 4 + 3] += xv * wv.w;
    }
  }
  if (n < NN) {
    #pragma unroll
    for (int j4 = 0; j4 < 8; ++j4) {
      float4 o;
      o.x = acc[j4 * 4 + 0]; o.y = acc[j4 * 4 + 1];
      o.z = acc[j4 * 4 + 2]; o.w = acc[j4 * 4 + 3];
      *(float4*)(xl + (size_t)n * 128 + w * 32 + j4 * 4) = o;
    }
    float ss = 0.f, sd = 0.f;
    #pragma unroll
    for (int j = 0; j < 32; ++j) {
      ss += acc[j] * att_src[w * 32 + j];
      sd += acc[j] * att_dst[w * 32 + j];
    }
    asrc[n * 4 + w] = ss;   // head == wave -> no reduction needed
    adst[n * 4 + w] = sd;
  }
}

// -------------------- layer-1 edge pass: exp(leaky(logits)), den atomics --------------------
__global__ void k_edge1(const int* __restrict__ ei, const float* __restrict__ eattr,
                        const float* __restrict__ asrc, const float* __restrict__ adst,
                        const float* __restrict__ coef, const float* __restrict__ easum,
                        float* __restrict__ ex1, float* __restrict__ den1) {
  int e = blockIdx.x * 256 + threadIdx.x;
  if (e >= ETOT) return;
  int s, d; float ea;
  if (e < EE) { s = ei[e]; d = ei[EE + e]; ea = eattr[e]; }
  else { s = d = e - EE; ea = easum[0] * (1.f / EE); }   // self-loop, mean attr
  float4 as = *(const float4*)(asrc + (size_t)s * 4);
  float4 ad = *(const float4*)(adst + (size_t)d * 4);
  float4 c = *(const float4*)(coef);
  float a0 = as.x + ad.x + ea * c.x;
  float a1 = as.y + ad.y + ea * c.y;
  float a2 = as.z + ad.z + ea * c.z;
  float a3 = as.w + ad.w + ea * c.w;
  a0 = a0 > 0.f ? a0 : NEG * a0;
  a1 = a1 > 0.f ? a1 : NEG * a1;
  a2 = a2 > 0.f ? a2 : NEG * a2;
  a3 = a3 > 0.f ? a3 : NEG * a3;
  // |alpha| <= ~1 for this data -> exp without max-subtraction is safe
  float4 ex;
  ex.x = expf(a0); ex.y = expf(a1); ex.z = expf(a2); ex.w = expf(a3);
  *(float4*)(ex1 + (size_t)e * 4) = ex;
  float* db = den1 + (size_t)d * 4;
  atomicAdd(db + 0, ex.x);
  atomicAdd(db + 1, ex.y);
  atomicAdd(db + 2, ex.z);
  atomicAdd(db + 3, ex.w);
}

// -------------------- layer-1 aggregation: out1[d] += w_e * xl[s] --------------------
// thread per (edge, 4 channels): 32 threads/edge, coalesced 512B gather + 4 atomics
__global__ void k_agg1(const int* __restrict__ ei, const float* __restrict__ ex1,
                       const float* __restrict__ den1, const float* __restrict__ xl,
                       float* __restrict__ out1) {
  int gid = blockIdx.x * 256 + threadIdx.x;   // grid exact: 850000*32
  int e = gid >> 5;
  int c4 = (gid & 31) << 2;
  int s, d;
  if (e < EE) { s = ei[e]; d = ei[EE + e]; }
  else { s = d = e - EE; }
  int h = c4 >> 5;
  float wv = ex1[(size_t)e * 4 + h] / den1[(size_t)d * 4 + h];
  float4 xv = *(const float4*)(xl + (size_t)s * 128 + c4);
  float* ob = out1 + (size_t)d * 128 + c4;
  atomicAdd(ob + 0, wv * xv.x);
  atomicAdd(ob + 1, wv * xv.y);
  atomicAdd(ob + 2, wv * xv.z);
  atomicAdd(ob + 3, wv * xv.w);
}

// -------------------- layer-2 GEMM: hl = elu(out1+bias1) @ W2, plus logits --------------------
__global__ __launch_bounds__(256) void k_lin2(
    const float* __restrict__ out1, const float* __restrict__ bias1,
    const float* __restrict__ W2,
    const float* __restrict__ as2w, const float* __restrict__ ad2w,
    float* __restrict__ hl, float* __restrict__ asrc2, float* __restrict__ adst2) {
  __shared__ float hT[128][65];
  const int n0 = blockIdx.x * 64;
  const int t = threadIdx.x;
  #pragma unroll
  for (int i = 0; i < 8; ++i) {
    int f = t + 256 * i;
    int n = f >> 5;
    int k4 = (f & 31) << 2;
    int nn = n0 + n;
    float4 v = make_float4(0.f, 0.f, 0.f, 0.f);
    if (nn < NN) v = *(const float4*)(out1 + (size_t)nn * 128 + k4);
    float4 b = *(const float4*)(bias1 + k4);
    v.x += b.x; v.y += b.y; v.z += b.z; v.w += b.w;
    v.x = v.x > 0.f ? v.x : (expf(v.x) - 1.f);   // ELU fused into staging
    v.y = v.y > 0.f ? v.y : (expf(v.y) - 1.f);
    v.z = v.z > 0.f ? v.z : (expf(v.z) - 1.f);
    v.w = v.w > 0.f ? v.w : (expf(v.w) - 1.f);
    hT[k4 + 0][n] = v.x;
    hT[k4 + 1][n] = v.y;
    hT[k4 + 2][n] = v.z;
    hT[k4 + 3][n] = v.w;
  }
  __syncthreads();
  const int w = t >> 6;
  const int lane = t & 63;
  const int n = n0 + lane;
  float acc[8];
  #pragma unroll
  for (int j = 0; j < 8; ++j) acc[j] = 0.f;
  for (int k = 0; k < 128; ++k) {
    float xv = hT[k][lane];
    const float4* Wr = (const float4*)(W2 + k * 32 + w * 8);
    float4 a = Wr[0], b = Wr[1];
    acc[0] += xv * a.x; acc[1] += xv * a.y; acc[2] += xv * a.z; acc[3] += xv * a.w;
    acc[4] += xv * b.x; acc[5] += xv * b.y; acc[6] += xv * b.z; acc[7] += xv * b.w;
  }
  if (n < NN) {
    float4 o1, o2;
    o1.x = acc[0]; o1.y = acc[1]; o1.z = acc[2]; o1.w = acc[3];
    o2.x = acc[4]; o2.y = acc[5]; o2.z = acc[6]; o2.w = acc[7];
    *(float4*)(hl + (size_t)n * 32 + w * 8) = o1;
    *(float4*)(hl + (size_t)n * 32 + w * 8 + 4) = o2;
    float ps = 0.f, pd = 0.f;
    #pragma unroll
    for (int j = 0; j < 8; ++j) {
      ps += acc[j] * as2w[w * 8 + j];
      pd += acc[j] * ad2w[w * 8 + j];
    }
    atomicAdd(asrc2 + n, ps);   // 4 waves contribute 8-channel partials
    atomicAdd(adst2 + n, pd);
  }
}

// -------------------- output init: out = bias2 --------------------
__global__ void k_out_init(float* __restrict__ out, const float* __restrict__ bias2) {
  int i = blockIdx.x * 256 + threadIdx.x;
  if (i < NN * 32) out[i] = bias2[i & 31];
}

// -------------------- layer-2 edge pass --------------------
__global__ void k_edge2(const int* __restrict__ ei, const float* __restrict__ eattr,
                        const float* __restrict__ as2, const float* __restrict__ ad2,
                        const float* __restrict__ coef, const float* __restrict__ easum,
                        float* __restrict__ ex2, float* __restrict__ den2) {
  int e = blockIdx.x * 256 + threadIdx.x;
  if (e >= ETOT) return;
  int s, d; float ea;
  if (e < EE) { s = ei[e]; d = ei[EE + e]; ea = eattr[e]; }
  else { s = d = e - EE; ea = easum[0] * (1.f / EE); }
  float a = as2[s] + ad2[d] + ea * coef[4];
  a = a > 0.f ? a : NEG * a;
  float ex = expf(a);
  ex2[e] = ex;
  atomicAdd(den2 + d, ex);
}

// -------------------- layer-2 aggregation --------------------
__global__ void k_agg2(const int* __restrict__ ei, const float* __restrict__ ex2,
                       const float* __restrict__ den2, const float* __restrict__ hl,
                       float* __restrict__ out) {
  int gid = blockIdx.x * 256 + threadIdx.x;
  if (gid >= ETOT * 8) return;
  int e = gid >> 3;
  int c4 = (gid & 7) << 2;
  int s, d;
  if (e < EE) { s = ei[e]; d = ei[EE + e]; }
  else { s = d = e - EE; }
  float wv = ex2[e] / den2[d];
  float4 hv = *(const float4*)(hl + (size_t)s * 32 + c4);
  float* ob = out + (size_t)d * 32 + c4;
  atomicAdd(ob + 0, wv * hv.x);
  atomicAdd(ob + 1, wv * hv.y);
  atomicAdd(ob + 2, wv * hv.z);
  atomicAdd(ob + 3, wv * hv.w);
}

extern "C" void kernel_launch(void* const* d_in, const int* in_sizes, int n_in,
                              void* d_out, int out_size, void* d_ws, size_t ws_size,
                              hipStream_t stream) {
  const float* x        = (const float*)d_in[0];
  const int*   ei       = (const int*)d_in[1];
  const float* eattr    = (const float*)d_in[2];
  const float* lin1_w   = (const float*)d_in[3];
  const float* att1_src = (const float*)d_in[4];
  const float* att1_dst = (const float*)d_in[5];
  const float* lin1_ew  = (const float*)d_in[6];
  const float* att1_e   = (const float*)d_in[7];
  const float* bias1    = (const float*)d_in[8];
  const float* lin2_w   = (const float*)d_in[9];
  const float* att2_src = (const float*)d_in[10];
  const float* att2_dst = (const float*)d_in[11];
  const float* lin2_ew  = (const float*)d_in[12];
  const float* att2_e   = (const float*)d_in[13];
  const float* bias2    = (const float*)d_in[14];
  float* out = (float*)d_out;
  float* ws  = (float*)d_ws;

  float* out1  = ws + O_OUT1;
  float* den1  = ws + O_DEN1;
  float* den2  = ws + O_DEN2;
  float* asrc2 = ws + O_ASRC2;
  float* adst2 = ws + O_ADST2;
  float* easum = ws + O_EASUM;
  float* coef  = ws + O_COEF;
  float* xl    = ws + O_XL;
  float* asrc1 = ws + O_ASRC1;
  float* adst1 = ws + O_ADST1;
  float* hl    = ws + O_HL;
  float* ex1   = ws + O_EX1;
  float* ex2   = ws + O_EX2;

  // zero out1/den1/den2/asrc2/adst2/easum in one shot (ws poisoned 0xAA each call)
  hipMemsetAsync(ws, 0, (size_t)ZERO_FLOATS * sizeof(float), stream);

  k_ea_reduce<<<256, 256, 0, stream>>>(eattr, easum);
  k_coef<<<1, 128, 0, stream>>>(lin1_ew, att1_e, lin2_ew, att2_e, coef);

  k_lin1<<<(NN + 63) / 64, 256, 0, stream>>>(x, lin1_w, att1_src, att1_dst, xl, asrc1, adst1);
  k_edge1<<<(ETOT + 255) / 256, 256, 0, stream>>>(ei, eattr, asrc1, adst1, coef, easum, ex1, den1);
  k_agg1<<<(ETOT * 32) / 256, 256, 0, stream>>>(ei, ex1, den1, xl, out1);

  k_lin2<<<(NN + 63) / 64, 256, 0, stream>>>(out1, bias1, lin2_w, att2_src, att2_dst, hl, asrc2, adst2);
  k_out_init<<<(NN * 32 + 255) / 256, 256, 0, stream>>>(out, bias2);
  k_edge2<<<(ETOT + 255) / 256, 256, 0, stream>>>(ei, eattr, asrc2, adst2, coef, easum, ex2, den2);
  k_agg2<<<(ETOT * 8 + 255) / 256, 256, 0, stream>>>(ei, ex2, den2, hl, out);
}

// Round 2
// 619.106 us; speedup vs baseline: 3.6533x; 3.6533x over previous
//
#include <hip/hip_runtime.h>
#include <math.h>

// GAT 2-layer, N=50000, E=800000 (+N self loops), IN=128, HID=32, HEADS=4, OUT=32
#define NN   50000
#define EE   800000
#define ETOT 850000          // EE + NN
#define NEG  0.2f

// -------- workspace layout (element offsets, 4B each; ints alias floats) --------
// zero-initialized region (one contiguous memset):
#define O_DEG    0           //    50,000  in-degree per node (int)
#define O_ASRC2  50000       //    50,000  per-node src logits layer2
#define O_ADST2  100000      //    50,000  per-node dst logits layer2
#define O_EASUM  150000      //         4  edge_attr sum (scalar)
#define ZERO_ELEMS 150004
// non-zeroed:
#define O_COEF   150004      //         8  coef1[4], coef2 at [4]
#define O_ROWPTR 150016      //    50,001  CSR row pointers (int)
#define O_CURSOR 200020      //    50,000  fill cursors (int)
#define O_CSRSRC 250020      //   850,000  src node per CSR slot (int)
#define O_SLOT   1100020     //   850,000  slot_of_edge (int)
#define O_XL     1950020     // 6,400,000  layer-1 features [N][128]
#define O_ASRC1  8350020     //   200,000  per-node src logits layer1 [N][4]
#define O_ADST1  8550020     //   200,000  per-node dst logits layer1 [N][4]
#define O_EXS1   8750020     // 3,400,000  exp(alpha1) in SLOT order [Etot][4]
#define O_OUT1   12150020    // 6,400,000  layer-1 agg output [N][128]
#define O_HL     O_EXS1      // 1,600,000  layer-2 features (aliases exs1: dead after k_agg1)
#define O_EXS2   O_XL        //   850,000  exp(alpha2) slot order (aliases xl: dead after k_agg1)
#define WS_ELEMS 18550020    // ~74.2 MB

// -------------------- edge_attr mean (sum) --------------------
__global__ void k_ea_reduce(const float* __restrict__ ea, float* __restrict__ easum) {
  __shared__ float red[4];
  float s = 0.f;
  int stride = gridDim.x * blockDim.x;
  for (int i = blockIdx.x * blockDim.x + threadIdx.x; i < EE; i += stride)
    s += ea[i];
  #pragma unroll
  for (int o = 32; o > 0; o >>= 1) s += __shfl_down(s, o, 64);
  if ((threadIdx.x & 63) == 0) red[threadIdx.x >> 6] = s;
  __syncthreads();
  if (threadIdx.x == 0) atomicAdd(easum, red[0] + red[1] + red[2] + red[3]);
}

// -------------------- edge-coef precompute --------------------
__global__ void k_coef(const float* __restrict__ lew1, const float* __restrict__ ae1,
                       const float* __restrict__ lew2, const float* __restrict__ ae2,
                       float* __restrict__ coef) {
  int t = threadIdx.x; // 128 threads
  float p = lew1[t] * ae1[t];
  #pragma unroll
  for (int o = 16; o > 0; o >>= 1) p += __shfl_down(p, o, 32);
  if ((t & 31) == 0) coef[t >> 5] = p;
  if (t < 32) {
    float q = lew2[t] * ae2[t];
    #pragma unroll
    for (int o = 16; o > 0; o >>= 1) q += __shfl_down(q, o, 32);
    if (t == 0) coef[4] = q;
  }
}

// -------------------- CSR build: count, scan, fill --------------------
__global__ void k_count(const int* __restrict__ ei, int* __restrict__ deg) {
  int e = blockIdx.x * 256 + threadIdx.x;
  if (e >= ETOT) return;
  int d = (e < EE) ? ei[EE + e] : e - EE;
  atomicAdd(deg + d, 1);
}

// single block, 1024 threads, 49 elems/thread; exclusive scan of deg -> rowptr, cursor
#define SCAN_CH 49
__global__ __launch_bounds__(1024) void k_scan(const int* __restrict__ deg,
                                               int* __restrict__ rowptr,
                                               int* __restrict__ cursor) {
  __shared__ int part[1024];
  const int t = threadIdx.x;
  const int base = t * SCAN_CH;
  int local[SCAN_CH];
  int s = 0;
  #pragma unroll
  for (int i = 0; i < SCAN_CH; ++i) {
    int idx = base + i;
    int v = (idx < NN) ? deg[idx] : 0;
    local[i] = s;
    s += v;
  }
  part[t] = s;
  __syncthreads();
  for (int o = 1; o < 1024; o <<= 1) {
    int v = (t >= o) ? part[t - o] : 0;
    __syncthreads();
    part[t] += v;
    __syncthreads();
  }
  int off = (t > 0) ? part[t - 1] : 0;
  #pragma unroll
  for (int i = 0; i < SCAN_CH; ++i) {
    int idx = base + i;
    if (idx < NN) {
      int r = off + local[i];
      rowptr[idx] = r;
      cursor[idx] = r;
    }
  }
  if (t == 0) rowptr[NN] = ETOT;
}

__global__ void k_fill(const int* __restrict__ ei, int* __restrict__ cursor,
                       int* __restrict__ csr_src, int* __restrict__ slot_of) {
  int e = blockIdx.x * 256 + threadIdx.x;
  if (e >= ETOT) return;
  int s, d;
  if (e < EE) { s = ei[e]; d = ei[EE + e]; }
  else { s = d = e - EE; }
  int slot = atomicAdd(cursor + d, 1);
  csr_src[slot] = s;
  slot_of[e] = slot;
}

// -------------------- layer-1 GEMM: xl = x @ W1, plus per-node logits --------------------
__global__ __launch_bounds__(256) void k_lin1(
    const float* __restrict__ x, const float* __restrict__ W,
    const float* __restrict__ att_src, const float* __restrict__ att_dst,
    float* __restrict__ xl, float* __restrict__ asrc, float* __restrict__ adst) {
  __shared__ float xT[128][65];
  const int n0 = blockIdx.x * 64;
  const int t = threadIdx.x;
  #pragma unroll
  for (int i = 0; i < 8; ++i) {
    int f = t + 256 * i;          // float4 index within 64x128 tile
    int n = f >> 5;
    int k4 = (f & 31) << 2;
    int nn = n0 + n;
    float4 v = make_float4(0.f, 0.f, 0.f, 0.f);
    if (nn < NN) v = *(const float4*)(x + (size_t)nn * 128 + k4);
    xT[k4 + 0][n] = v.x;
    xT[k4 + 1][n] = v.y;
    xT[k4 + 2][n] = v.z;
    xT[k4 + 3][n] = v.w;
  }
  __syncthreads();
  const int w = t >> 6;       // head / wave id
  const int lane = t & 63;    // node within tile
  const int n = n0 + lane;
  float acc[32];
  #pragma unroll
  for (int j = 0; j < 32; ++j) acc[j] = 0.f;
  for (int k = 0; k < 128; ++k) {
    float xv = xT[k][lane];
    const float4* Wr = (const float4*)(W + k * 128 + w * 32);  // wave-uniform
    #pragma unroll
    for (int j4 = 0; j4 < 8; ++j4) {
      float4 wv = Wr[j4];
      acc[j4 * 4 + 0] += xv * wv.x;
      acc[j4 * 4 + 1] += xv * wv.y;
      acc[j4 * 4 + 2] += xv * wv.z;
      acc[j4 * 4 + 3] += xv * wv.w;
    }
  }
  if (n < NN) {
    #pragma unroll
    for (int j4 = 0; j4 < 8; ++j4) {
      float4 o;
      o.x = acc[j4 * 4 + 0]; o.y = acc[j4 * 4 + 1];
      o.z = acc[j4 * 4 + 2]; o.w = acc[j4 * 4 + 3];
      *(float4*)(xl + (size_t)n * 128 + w * 32 + j4 * 4) = o;
    }
    float ss = 0.f, sd = 0.f;
    #pragma unroll
    for (int j = 0; j < 32; ++j) {
      ss += acc[j] * att_src[w * 32 + j];
      sd += acc[j] * att_dst[w * 32 + j];
    }
    asrc[n * 4 + w] = ss;   // head == wave -> no reduction needed
    adst[n * 4 + w] = sd;
  }
}

// -------------------- layer-1 edge pass: exp(leaky(logits)) scattered to slot order ----
__global__ void k_edge1(const int* __restrict__ ei, const float* __restrict__ eattr,
                        const float* __restrict__ asrc, const float* __restrict__ adst,
                        const float* __restrict__ coef, const float* __restrict__ easum,
                        const int* __restrict__ slot_of, float* __restrict__ exs1) {
  int e = blockIdx.x * 256 + threadIdx.x;
  if (e >= ETOT) return;
  int s, d; float ea;
  if (e < EE) { s = ei[e]; d = ei[EE + e]; ea = eattr[e]; }
  else { s = d = e - EE; ea = easum[0] * (1.f / EE); }   // self-loop, mean attr
  float4 as = *(const float4*)(asrc + (size_t)s * 4);
  float4 ad = *(const float4*)(adst + (size_t)d * 4);
  float4 c = *(const float4*)(coef);
  float a0 = as.x + ad.x + ea * c.x;
  float a1 = as.y + ad.y + ea * c.y;
  float a2 = as.z + ad.z + ea * c.z;
  float a3 = as.w + ad.w + ea * c.w;
  a0 = a0 > 0.f ? a0 : NEG * a0;
  a1 = a1 > 0.f ? a1 : NEG * a1;
  a2 = a2 > 0.f ? a2 : NEG * a2;
  a3 = a3 > 0.f ? a3 : NEG * a3;
  // |alpha| <= ~1 for this data -> exp without max-subtraction is safe
  float4 ex;
  ex.x = expf(a0); ex.y = expf(a1); ex.z = expf(a2); ex.w = expf(a3);
  *(float4*)(exs1 + (size_t)slot_of[e] * 4) = ex;
}

// -------------------- layer-1 aggregation: gather per node, no atomics --------------------
// one wave per node; lane handles channels {lane, lane+64}; den accumulated redundantly
__global__ __launch_bounds__(256) void k_agg1(
    const int* __restrict__ rowptr, const int* __restrict__ csr_src,
    const float* __restrict__ exs1, const float* __restrict__ xl,
    float* __restrict__ out1) {
  int n = blockIdx.x * 4 + (threadIdx.x >> 6);
  if (n >= NN) return;
  int lane = threadIdx.x & 63;
  int h0 = lane >> 5;                 // head of channel `lane` (0/1)
  int r0 = rowptr[n], r1 = rowptr[n + 1];
  float acc0 = 0.f, acc1 = 0.f, den0 = 0.f, den1 = 0.f;
  for (int j = r0; j < r1; ++j) {
    int s = csr_src[j];
    float exA = exs1[(size_t)j * 4 + h0];
    float exB = exs1[(size_t)j * 4 + 2 + h0];
    const float* xb = xl + (size_t)s * 128;
    float xA = xb[lane];
    float xB = xb[64 + lane];
    acc0 += exA * xA; den0 += exA;
    acc1 += exB * xB; den1 += exB;
  }
  out1[(size_t)n * 128 + lane]      = acc0 / den0;
  out1[(size_t)n * 128 + 64 + lane] = acc1 / den1;
}

// -------------------- layer-2 GEMM: hl = elu(out1+bias1) @ W2, plus logits --------------------
__global__ __launch_bounds__(256) void k_lin2(
    const float* __restrict__ out1, const float* __restrict__ bias1,
    const float* __restrict__ W2,
    const float* __restrict__ as2w, const float* __restrict__ ad2w,
    float* __restrict__ hl, float* __restrict__ asrc2, float* __restrict__ adst2) {
  __shared__ float hT[128][65];
  const int n0 = blockIdx.x * 64;
  const int t = threadIdx.x;
  #pragma unroll
  for (int i = 0; i < 8; ++i) {
    int f = t + 256 * i;
    int n = f >> 5;
    int k4 = (f & 31) << 2;
    int nn = n0 + n;
    float4 v = make_float4(0.f, 0.f, 0.f, 0.f);
    if (nn < NN) v = *(const float4*)(out1 + (size_t)nn * 128 + k4);
    float4 b = *(const float4*)(bias1 + k4);
    v.x += b.x; v.y += b.y; v.z += b.z; v.w += b.w;
    v.x = v.x > 0.f ? v.x : (expf(v.x) - 1.f);   // ELU fused into staging
    v.y = v.y > 0.f ? v.y : (expf(v.y) - 1.f);
    v.z = v.z > 0.f ? v.z : (expf(v.z) - 1.f);
    v.w = v.w > 0.f ? v.w : (expf(v.w) - 1.f);
    hT[k4 + 0][n] = v.x;
    hT[k4 + 1][n] = v.y;
    hT[k4 + 2][n] = v.z;
    hT[k4 + 3][n] = v.w;
  }
  __syncthreads();
  const int w = t >> 6;
  const int lane = t & 63;
  const int n = n0 + lane;
  float acc[8];
  #pragma unroll
  for (int j = 0; j < 8; ++j) acc[j] = 0.f;
  for (int k = 0; k < 128; ++k) {
    float xv = hT[k][lane];
    const float4* Wr = (const float4*)(W2 + k * 32 + w * 8);
    float4 a = Wr[0], b = Wr[1];
    acc[0] += xv * a.x; acc[1] += xv * a.y; acc[2] += xv * a.z; acc[3] += xv * a.w;
    acc[4] += xv * b.x; acc[5] += xv * b.y; acc[6] += xv * b.z; acc[7] += xv * b.w;
  }
  if (n < NN) {
    float4 o1, o2;
    o1.x = acc[0]; o1.y = acc[1]; o1.z = acc[2]; o1.w = acc[3];
    o2.x = acc[4]; o2.y = acc[5]; o2.z = acc[6]; o2.w = acc[7];
    *(float4*)(hl + (size_t)n * 32 + w * 8) = o1;
    *(float4*)(hl + (size_t)n * 32 + w * 8 + 4) = o2;
    float ps = 0.f, pd = 0.f;
    #pragma unroll
    for (int j = 0; j < 8; ++j) {
      ps += acc[j] * as2w[w * 8 + j];
      pd += acc[j] * ad2w[w * 8 + j];
    }
    atomicAdd(asrc2 + n, ps);   // 4 waves contribute 8-channel partials
    atomicAdd(adst2 + n, pd);
  }
}

// -------------------- layer-2 edge pass --------------------
__global__ void k_edge2(const int* __restrict__ ei, const float* __restrict__ eattr,
                        const float* __restrict__ as2, const float* __restrict__ ad2,
                        const float* __restrict__ coef, const float* __restrict__ easum,
                        const int* __restrict__ slot_of, float* __restrict__ exs2) {
  int e = blockIdx.x * 256 + threadIdx.x;
  if (e >= ETOT) return;
  int s, d; float ea;
  if (e < EE) { s = ei[e]; d = ei[EE + e]; ea = eattr[e]; }
  else { s = d = e - EE; ea = easum[0] * (1.f / EE); }
  float a = as2[s] + ad2[d] + ea * coef[4];
  a = a > 0.f ? a : NEG * a;
  exs2[slot_of[e]] = expf(a);
}

// -------------------- layer-2 aggregation: half-wave per node, fused bias2 ---------------
__global__ __launch_bounds__(256) void k_agg2(
    const int* __restrict__ rowptr, const int* __restrict__ csr_src,
    const float* __restrict__ exs2, const float* __restrict__ hl,
    const float* __restrict__ bias2, float* __restrict__ out) {
  int n = blockIdx.x * 8 + (threadIdx.x >> 5);
  if (n >= NN) return;
  int c = threadIdx.x & 31;
  int r0 = rowptr[n], r1 = rowptr[n + 1];
  float acc = 0.f, den = 0.f;
  for (int j = r0; j < r1; ++j) {
    int s = csr_src[j];
    float ex = exs2[j];
    acc += ex * hl[(size_t)s * 32 + c];
    den += ex;
  }
  out[(size_t)n * 32 + c] = acc / den + bias2[c];
}

extern "C" void kernel_launch(void* const* d_in, const int* in_sizes, int n_in,
                              void* d_out, int out_size, void* d_ws, size_t ws_size,
                              hipStream_t stream) {
  const float* x        = (const float*)d_in[0];
  const int*   ei       = (const int*)d_in[1];
  const float* eattr    = (const float*)d_in[2];
  const float* lin1_w   = (const float*)d_in[3];
  const float* att1_src = (const float*)d_in[4];
  const float* att1_dst = (const float*)d_in[5];
  const float* lin1_ew  = (const float*)d_in[6];
  const float* att1_e   = (const float*)d_in[7];
  const float* bias1    = (const float*)d_in[8];
  const float* lin2_w   = (const float*)d_in[9];
  const float* att2_src = (const float*)d_in[10];
  const float* att2_dst = (const float*)d_in[11];
  const float* lin2_ew  = (const float*)d_in[12];
  const float* att2_e   = (const float*)d_in[13];
  const float* bias2    = (const float*)d_in[14];
  float* out = (float*)d_out;
  float* ws  = (float*)d_ws;
  int*   wsi = (int*)d_ws;

  int*   deg     = wsi + O_DEG;
  float* asrc2   = ws + O_ASRC2;
  float* adst2   = ws + O_ADST2;
  float* easum   = ws + O_EASUM;
  float* coef    = ws + O_COEF;
  int*   rowptr  = wsi + O_ROWPTR;
  int*   cursor  = wsi + O_CURSOR;
  int*   csr_src = wsi + O_CSRSRC;
  int*   slot_of = wsi + O_SLOT;
  float* xl      = ws + O_XL;
  float* asrc1   = ws + O_ASRC1;
  float* adst1   = ws + O_ADST1;
  float* exs1    = ws + O_EXS1;
  float* out1    = ws + O_OUT1;
  float* hl      = ws + O_HL;    // aliases exs1 (dead after k_agg1)
  float* exs2    = ws + O_EXS2;  // aliases xl   (dead after k_agg1)

  // zero deg/asrc2/adst2/easum in one shot (ws poisoned 0xAA each call)
  hipMemsetAsync(ws, 0, (size_t)ZERO_ELEMS * sizeof(float), stream);

  k_ea_reduce<<<256, 256, 0, stream>>>(eattr, easum);
  k_coef<<<1, 128, 0, stream>>>(lin1_ew, att1_e, lin2_ew, att2_e, coef);

  // CSR build (dst-sorted)
  k_count<<<(ETOT + 255) / 256, 256, 0, stream>>>(ei, deg);
  k_scan<<<1, 1024, 0, stream>>>(deg, rowptr, cursor);
  k_fill<<<(ETOT + 255) / 256, 256, 0, stream>>>(ei, cursor, csr_src, slot_of);

  // layer 1
  k_lin1<<<(NN + 63) / 64, 256, 0, stream>>>(x, lin1_w, att1_src, att1_dst, xl, asrc1, adst1);
  k_edge1<<<(ETOT + 255) / 256, 256, 0, stream>>>(ei, eattr, asrc1, adst1, coef, easum, slot_of, exs1);
  k_agg1<<<(NN + 3) / 4, 256, 0, stream>>>(rowptr, csr_src, exs1, xl, out1);

  // layer 2
  k_lin2<<<(NN + 63) / 64, 256, 0, stream>>>(out1, bias1, lin2_w, att2_src, att2_dst, hl, asrc2, adst2);
  k_edge2<<<(ETOT + 255) / 256, 256, 0, stream>>>(ei, eattr, asrc2, adst2, coef, easum, slot_of, exs2);
  k_agg2<<<(NN + 7) / 8, 256, 0, stream>>>(rowptr, csr_src, exs2, hl, bias2, out);
}

// Round 3
// 523.646 us; speedup vs baseline: 4.3193x; 1.1823x over previous
//
#include <hip/hip_runtime.h>
#include <math.h>

// GAT 2-layer, N=50000, E=800000 (+N self loops), IN=128, HID=32, HEADS=4, OUT=32
#define NN   50000
#define EE   800000
#define ETOT 850000          // EE + NN
#define NEG  0.2f

// -------- workspace layout (element offsets, 4B each; ints alias floats) --------
// zero-initialized region (one contiguous memset):
#define O_DEG    0           //    50,000  in-degree per node (int)
#define O_EASUM  50000       //         4  edge_attr sum (scalar)
#define ZERO_ELEMS 50004
// non-zeroed:
#define O_COEF   50004       //         8  coef1[4], coef2 at [4]
#define O_ROWPTR 50012       //    50,001  CSR row pointers (int)
#define O_CURSOR 100016      //    50,000  fill cursors (int)
#define O_CSRSRC 150016      //   850,000  src node per CSR slot (int)
#define O_SLOT   1000016     //   850,000  slot_of_edge (int)
#define O_XL     1850016     // 6,400,000  layer-1 features [N][128]
#define O_ASRC1  8250016     //   200,000  per-node src logits layer1 [N][4]
#define O_ADST1  8450016     //   200,000  per-node dst logits layer1 [N][4]
#define O_EXS1   8650016     // 3,400,000  exp(alpha1) in SLOT order [Etot][4]
#define O_OUT1   12050016    // 6,400,000  layer-1 agg output [N][128]
#define O_ASRC2  18450016    //    50,000  per-node src logits layer2
#define O_ADST2  18500016    //    50,000  per-node dst logits layer2
#define O_HL     O_EXS1      // 1,600,000  layer-2 features (aliases exs1: dead after k_agg1)
#define O_EXS2   O_XL        //   850,000  exp(alpha2) slot order (aliases xl: dead after k_agg1)
#define WS_ELEMS 18550016    // ~74.2 MB

// -------------------- edge_attr mean (sum) --------------------
__global__ void k_ea_reduce(const float* __restrict__ ea, float* __restrict__ easum) {
  __shared__ float red[4];
  float s = 0.f;
  int stride = gridDim.x * blockDim.x;
  for (int i = blockIdx.x * blockDim.x + threadIdx.x; i < EE; i += stride)
    s += ea[i];
  #pragma unroll
  for (int o = 32; o > 0; o >>= 1) s += __shfl_down(s, o, 64);
  if ((threadIdx.x & 63) == 0) red[threadIdx.x >> 6] = s;
  __syncthreads();
  if (threadIdx.x == 0) atomicAdd(easum, red[0] + red[1] + red[2] + red[3]);
}

// -------------------- edge-coef precompute --------------------
__global__ void k_coef(const float* __restrict__ lew1, const float* __restrict__ ae1,
                       const float* __restrict__ lew2, const float* __restrict__ ae2,
                       float* __restrict__ coef) {
  int t = threadIdx.x; // 128 threads
  float p = lew1[t] * ae1[t];
  #pragma unroll
  for (int o = 16; o > 0; o >>= 1) p += __shfl_down(p, o, 32);
  if ((t & 31) == 0) coef[t >> 5] = p;
  if (t < 32) {
    float q = lew2[t] * ae2[t];
    #pragma unroll
    for (int o = 16; o > 0; o >>= 1) q += __shfl_down(q, o, 32);
    if (t == 0) coef[4] = q;
  }
}

// -------------------- CSR build: count, scan, fill --------------------
__global__ void k_count(const int* __restrict__ ei, int* __restrict__ deg) {
  int e = blockIdx.x * 256 + threadIdx.x;
  if (e >= ETOT) return;
  int d = (e < EE) ? ei[EE + e] : e - EE;
  atomicAdd(deg + d, 1);
}

// single block, 1024 threads, 49 elems/thread; exclusive scan of deg -> rowptr, cursor
#define SCAN_CH 49
__global__ __launch_bounds__(1024) void k_scan(const int* __restrict__ deg,
                                               int* __restrict__ rowptr,
                                               int* __restrict__ cursor) {
  __shared__ int part[1024];
  const int t = threadIdx.x;
  const int base = t * SCAN_CH;
  int local[SCAN_CH];
  int s = 0;
  #pragma unroll
  for (int i = 0; i < SCAN_CH; ++i) {
    int idx = base + i;
    int v = (idx < NN) ? deg[idx] : 0;
    local[i] = s;
    s += v;
  }
  part[t] = s;
  __syncthreads();
  for (int o = 1; o < 1024; o <<= 1) {
    int v = (t >= o) ? part[t - o] : 0;
    __syncthreads();
    part[t] += v;
    __syncthreads();
  }
  int off = (t > 0) ? part[t - 1] : 0;
  #pragma unroll
  for (int i = 0; i < SCAN_CH; ++i) {
    int idx = base + i;
    if (idx < NN) {
      int r = off + local[i];
      rowptr[idx] = r;
      cursor[idx] = r;
    }
  }
  if (t == 0) rowptr[NN] = ETOT;
}

__global__ void k_fill(const int* __restrict__ ei, int* __restrict__ cursor,
                       int* __restrict__ csr_src, int* __restrict__ slot_of) {
  int e = blockIdx.x * 256 + threadIdx.x;
  if (e >= ETOT) return;
  int s, d;
  if (e < EE) { s = ei[e]; d = ei[EE + e]; }
  else { s = d = e - EE; }
  int slot = atomicAdd(cursor + d, 1);
  csr_src[slot] = s;
  slot_of[e] = slot;
}

// -------------------- layer-1 GEMM: xl = x @ W1, plus per-node logits --------------------
// W staged through LDS in double-buffered 16-k tiles (kills L1 thrash on 64KB W).
#define LTK 16
__global__ __launch_bounds__(256) void k_lin1(
    const float* __restrict__ x, const float* __restrict__ W,
    const float* __restrict__ att_src, const float* __restrict__ att_dst,
    float* __restrict__ xl, float* __restrict__ asrc, float* __restrict__ adst) {
  __shared__ float xT[128][65];       // 33,280 B
  __shared__ float Wt[2][LTK * 128];  // 16,384 B  -> total ~49.7 KB, 3 blocks/CU
  const int n0 = blockIdx.x * 64;
  const int t = threadIdx.x;
  // stage x tile (transposed)
  #pragma unroll
  for (int i = 0; i < 8; ++i) {
    int f = t + 256 * i;          // float4 index within 64x128 tile
    int n = f >> 5;
    int k4 = (f & 31) << 2;
    int nn = n0 + n;
    float4 v = make_float4(0.f, 0.f, 0.f, 0.f);
    if (nn < NN) v = *(const float4*)(x + (size_t)nn * 128 + k4);
    xT[k4 + 0][n] = v.x;
    xT[k4 + 1][n] = v.y;
    xT[k4 + 2][n] = v.z;
    xT[k4 + 3][n] = v.w;
  }
  // stage W tile 0 (2048 floats = 512 float4)
  {
    const float4* src = (const float4*)W;
    float4* dst = (float4*)Wt[0];
    dst[t] = src[t];
    dst[t + 256] = src[t + 256];
  }
  __syncthreads();
  const int w = t >> 6;       // head / wave id
  const int lane = t & 63;    // node within tile
  const int n = n0 + lane;
  float acc[32];
  #pragma unroll
  for (int j = 0; j < 32; ++j) acc[j] = 0.f;
  for (int T = 0; T < 8; ++T) {
    const int buf = T & 1;
    float4 p0, p1;
    if (T < 7) {   // prefetch next W tile into regs (latency hidden by FMAs below)
      const float4* src = (const float4*)(W + (T + 1) * LTK * 128);
      p0 = src[t];
      p1 = src[t + 256];
    }
    #pragma unroll
    for (int kk = 0; kk < LTK; ++kk) {
      float xv = xT[T * LTK + kk][lane];
      const float4* Wr = (const float4*)(&Wt[buf][kk * 128 + w * 32]);  // broadcast
      #pragma unroll
      for (int j4 = 0; j4 < 8; ++j4) {
        float4 wv = Wr[j4];
        acc[j4 * 4 + 0] += xv * wv.x;
        acc[j4 * 4 + 1] += xv * wv.y;
        acc[j4 * 4 + 2] += xv * wv.z;
        acc[j4 * 4 + 3] += xv * wv.w;
      }
    }
    if (T < 7) {   // idle buffer: everyone finished reading it at previous barrier
      float4* dst = (float4*)Wt[buf ^ 1];
      dst[t] = p0;
      dst[t + 256] = p1;
    }
    __syncthreads();
  }
  if (n < NN) {
    #pragma unroll
    for (int j4 = 0; j4 < 8; ++j4) {
      float4 o;
      o.x = acc[j4 * 4 + 0]; o.y = acc[j4 * 4 + 1];
      o.z = acc[j4 * 4 + 2]; o.w = acc[j4 * 4 + 3];
      *(float4*)(xl + (size_t)n * 128 + w * 32 + j4 * 4) = o;
    }
    float ss = 0.f, sd = 0.f;
    #pragma unroll
    for (int j = 0; j < 32; ++j) {
      ss += acc[j] * att_src[w * 32 + j];
      sd += acc[j] * att_dst[w * 32 + j];
    }
    asrc[n * 4 + w] = ss;   // head == wave -> no reduction needed
    adst[n * 4 + w] = sd;
  }
}

// -------------------- layer-1 edge pass: exp(leaky(logits)) scattered to slot order ----
__global__ void k_edge1(const int* __restrict__ ei, const float* __restrict__ eattr,
                        const float* __restrict__ asrc, const float* __restrict__ adst,
                        const float* __restrict__ coef, const float* __restrict__ easum,
                        const int* __restrict__ slot_of, float* __restrict__ exs1) {
  int e = blockIdx.x * 256 + threadIdx.x;
  if (e >= ETOT) return;
  int s, d; float ea;
  if (e < EE) { s = ei[e]; d = ei[EE + e]; ea = eattr[e]; }
  else { s = d = e - EE; ea = easum[0] * (1.f / EE); }   // self-loop, mean attr
  float4 as = *(const float4*)(asrc + (size_t)s * 4);
  float4 ad = *(const float4*)(adst + (size_t)d * 4);
  float4 c = *(const float4*)(coef);
  float a0 = as.x + ad.x + ea * c.x;
  float a1 = as.y + ad.y + ea * c.y;
  float a2 = as.z + ad.z + ea * c.z;
  float a3 = as.w + ad.w + ea * c.w;
  a0 = a0 > 0.f ? a0 : NEG * a0;
  a1 = a1 > 0.f ? a1 : NEG * a1;
  a2 = a2 > 0.f ? a2 : NEG * a2;
  a3 = a3 > 0.f ? a3 : NEG * a3;
  // |alpha| <= ~1 for this data -> exp without max-subtraction is safe
  float4 ex;
  ex.x = expf(a0); ex.y = expf(a1); ex.z = expf(a2); ex.w = expf(a3);
  *(float4*)(exs1 + (size_t)slot_of[e] * 4) = ex;
}

// -------------------- layer-1 aggregation: gather per node, no atomics --------------------
// one wave per node; lane handles channels {2*lane, 2*lane+1} (one head per lane);
// csr_src/ex prefetched one edge ahead to break the s->gather dependency chain.
__global__ __launch_bounds__(256) void k_agg1(
    const int* __restrict__ rowptr, const int* __restrict__ csr_src,
    const float* __restrict__ exs1, const float* __restrict__ xl,
    float* __restrict__ out1) {
  int n = blockIdx.x * 4 + (threadIdx.x >> 6);
  if (n >= NN) return;
  int lane = threadIdx.x & 63;
  int c = lane << 1;
  int h = c >> 5;                     // head of this lane's channel pair
  int r0 = rowptr[n], r1 = rowptr[n + 1];   // r1 > r0 (self-loop)
  float a0 = 0.f, a1 = 0.f, den = 0.f;
  int s = csr_src[r0];
  float ex = exs1[(size_t)r0 * 4 + h];
  for (int j = r0; j < r1; ++j) {
    int sc = s; float exc = ex;
    if (j + 1 < r1) {                 // wave-uniform branch
      s = csr_src[j + 1];
      ex = exs1[(size_t)(j + 1) * 4 + h];
    }
    float2 xv = *(const float2*)(xl + (size_t)sc * 128 + c);
    a0 += exc * xv.x;
    a1 += exc * xv.y;
    den += exc;
  }
  float inv = 1.f / den;
  *(float2*)(out1 + (size_t)n * 128 + c) = make_float2(a0 * inv, a1 * inv);
}

// -------------------- layer-2 GEMM: hl = elu(out1+bias1) @ W2, plus logits --------------------
__global__ __launch_bounds__(256) void k_lin2(
    const float* __restrict__ out1, const float* __restrict__ bias1,
    const float* __restrict__ W2,
    const float* __restrict__ as2w, const float* __restrict__ ad2w,
    float* __restrict__ hl, float* __restrict__ asrc2, float* __restrict__ adst2) {
  __shared__ float hT[128][65];      // 33,280 B
  __shared__ float W2l[128 * 32];    // 16,384 B
  __shared__ float psh[4][64], pdh[4][64];  // 2,048 B -> total ~51.7 KB, 3 blocks/CU
  const int n0 = blockIdx.x * 64;
  const int t = threadIdx.x;
  // stage W2 fully (4096 floats = 1024 float4)
  {
    const float4* src = (const float4*)W2;
    float4* dst = (float4*)W2l;
    #pragma unroll
    for (int i = 0; i < 4; ++i) dst[t + 256 * i] = src[t + 256 * i];
  }
  #pragma unroll
  for (int i = 0; i < 8; ++i) {
    int f = t + 256 * i;
    int n = f >> 5;
    int k4 = (f & 31) << 2;
    int nn = n0 + n;
    float4 v = make_float4(0.f, 0.f, 0.f, 0.f);
    if (nn < NN) v = *(const float4*)(out1 + (size_t)nn * 128 + k4);
    float4 b = *(const float4*)(bias1 + k4);
    v.x += b.x; v.y += b.y; v.z += b.z; v.w += b.w;
    v.x = v.x > 0.f ? v.x : (expf(v.x) - 1.f);   // ELU fused into staging
    v.y = v.y > 0.f ? v.y : (expf(v.y) - 1.f);
    v.z = v.z > 0.f ? v.z : (expf(v.z) - 1.f);
    v.w = v.w > 0.f ? v.w : (expf(v.w) - 1.f);
    hT[k4 + 0][n] = v.x;
    hT[k4 + 1][n] = v.y;
    hT[k4 + 2][n] = v.z;
    hT[k4 + 3][n] = v.w;
  }
  __syncthreads();
  const int w = t >> 6;
  const int lane = t & 63;
  const int n = n0 + lane;
  float acc[8];
  #pragma unroll
  for (int j = 0; j < 8; ++j) acc[j] = 0.f;
  for (int k = 0; k < 128; ++k) {
    float xv = hT[k][lane];
    const float4* Wr = (const float4*)(&W2l[k * 32 + w * 8]);  // broadcast
    float4 a = Wr[0], b = Wr[1];
    acc[0] += xv * a.x; acc[1] += xv * a.y; acc[2] += xv * a.z; acc[3] += xv * a.w;
    acc[4] += xv * b.x; acc[5] += xv * b.y; acc[6] += xv * b.z; acc[7] += xv * b.w;
  }
  float ps = 0.f, pd = 0.f;
  if (n < NN) {
    float4 o1, o2;
    o1.x = acc[0]; o1.y = acc[1]; o1.z = acc[2]; o1.w = acc[3];
    o2.x = acc[4]; o2.y = acc[5]; o2.z = acc[6]; o2.w = acc[7];
    *(float4*)(hl + (size_t)n * 32 + w * 8) = o1;
    *(float4*)(hl + (size_t)n * 32 + w * 8 + 4) = o2;
    #pragma unroll
    for (int j = 0; j < 8; ++j) {
      ps += acc[j] * as2w[w * 8 + j];
      pd += acc[j] * ad2w[w * 8 + j];
    }
  }
  psh[w][lane] = ps;
  pdh[w][lane] = pd;
  __syncthreads();
  if (w == 0 && n < NN) {    // cross-wave reduce, plain stores (no atomics / no memset dep)
    asrc2[n] = psh[0][lane] + psh[1][lane] + psh[2][lane] + psh[3][lane];
    adst2[n] = pdh[0][lane] + pdh[1][lane] + pdh[2][lane] + pdh[3][lane];
  }
}

// -------------------- layer-2 edge pass --------------------
__global__ void k_edge2(const int* __restrict__ ei, const float* __restrict__ eattr,
                        const float* __restrict__ as2, const float* __restrict__ ad2,
                        const float* __restrict__ coef, const float* __restrict__ easum,
                        const int* __restrict__ slot_of, float* __restrict__ exs2) {
  int e = blockIdx.x * 256 + threadIdx.x;
  if (e >= ETOT) return;
  int s, d; float ea;
  if (e < EE) { s = ei[e]; d = ei[EE + e]; ea = eattr[e]; }
  else { s = d = e - EE; ea = easum[0] * (1.f / EE); }
  float a = as2[s] + ad2[d] + ea * coef[4];
  a = a > 0.f ? a : NEG * a;
  exs2[slot_of[e]] = expf(a);
}

// -------------------- layer-2 aggregation: 16 lanes x float2 per node, fused bias2 -------
__global__ __launch_bounds__(256) void k_agg2(
    const int* __restrict__ rowptr, const int* __restrict__ csr_src,
    const float* __restrict__ exs2, const float* __restrict__ hl,
    const float* __restrict__ bias2, float* __restrict__ out) {
  int n = blockIdx.x * 16 + (threadIdx.x >> 4);
  if (n >= NN) return;
  int c = (threadIdx.x & 15) << 1;
  int r0 = rowptr[n], r1 = rowptr[n + 1];
  float a0 = 0.f, a1 = 0.f, den = 0.f;
  int s = csr_src[r0];
  float ex = exs2[r0];
  for (int j = r0; j < r1; ++j) {
    int sc = s; float exc = ex;
    if (j + 1 < r1) {
      s = csr_src[j + 1];
      ex = exs2[j + 1];
    }
    float2 hv = *(const float2*)(hl + (size_t)sc * 32 + c);
    a0 += exc * hv.x;
    a1 += exc * hv.y;
    den += exc;
  }
  float inv = 1.f / den;
  out[(size_t)n * 32 + c]     = a0 * inv + bias2[c];
  out[(size_t)n * 32 + c + 1] = a1 * inv + bias2[c + 1];
}

extern "C" void kernel_launch(void* const* d_in, const int* in_sizes, int n_in,
                              void* d_out, int out_size, void* d_ws, size_t ws_size,
                              hipStream_t stream) {
  const float* x        = (const float*)d_in[0];
  const int*   ei       = (const int*)d_in[1];
  const float* eattr    = (const float*)d_in[2];
  const float* lin1_w   = (const float*)d_in[3];
  const float* att1_src = (const float*)d_in[4];
  const float* att1_dst = (const float*)d_in[5];
  const float* lin1_ew  = (const float*)d_in[6];
  const float* att1_e   = (const float*)d_in[7];
  const float* bias1    = (const float*)d_in[8];
  const float* lin2_w   = (const float*)d_in[9];
  const float* att2_src = (const float*)d_in[10];
  const float* att2_dst = (const float*)d_in[11];
  const float* lin2_ew  = (const float*)d_in[12];
  const float* att2_e   = (const float*)d_in[13];
  const float* bias2    = (const float*)d_in[14];
  float* out = (float*)d_out;
  float* ws  = (float*)d_ws;
  int*   wsi = (int*)d_ws;

  int*   deg     = wsi + O_DEG;
  float* easum   = ws + O_EASUM;
  float* coef    = ws + O_COEF;
  int*   rowptr  = wsi + O_ROWPTR;
  int*   cursor  = wsi + O_CURSOR;
  int*   csr_src = wsi + O_CSRSRC;
  int*   slot_of = wsi + O_SLOT;
  float* xl      = ws + O_XL;
  float* asrc1   = ws + O_ASRC1;
  float* adst1   = ws + O_ADST1;
  float* exs1    = ws + O_EXS1;
  float* out1    = ws + O_OUT1;
  float* asrc2   = ws + O_ASRC2;
  float* adst2   = ws + O_ADST2;
  float* hl      = ws + O_HL;    // aliases exs1 (dead after k_agg1)
  float* exs2    = ws + O_EXS2;  // aliases xl   (dead after k_agg1)

  // zero deg/easum (ws poisoned 0xAA each call)
  hipMemsetAsync(ws, 0, (size_t)ZERO_ELEMS * sizeof(float), stream);

  k_ea_reduce<<<256, 256, 0, stream>>>(eattr, easum);
  k_coef<<<1, 128, 0, stream>>>(lin1_ew, att1_e, lin2_ew, att2_e, coef);

  // CSR build (dst-sorted)
  k_count<<<(ETOT + 255) / 256, 256, 0, stream>>>(ei, deg);
  k_scan<<<1, 1024, 0, stream>>>(deg, rowptr, cursor);
  k_fill<<<(ETOT + 255) / 256, 256, 0, stream>>>(ei, cursor, csr_src, slot_of);

  // layer 1
  k_lin1<<<(NN + 63) / 64, 256, 0, stream>>>(x, lin1_w, att1_src, att1_dst, xl, asrc1, adst1);
  k_edge1<<<(ETOT + 255) / 256, 256, 0, stream>>>(ei, eattr, asrc1, adst1, coef, easum, slot_of, exs1);
  k_agg1<<<(NN + 3) / 4, 256, 0, stream>>>(rowptr, csr_src, exs1, xl, out1);

  // layer 2
  k_lin2<<<(NN + 63) / 64, 256, 0, stream>>>(out1, bias1, lin2_w, att2_src, att2_dst, hl, asrc2, adst2);
  k_edge2<<<(ETOT + 255) / 256, 256, 0, stream>>>(ei, eattr, asrc2, adst2, coef, easum, slot_of, exs2);
  k_agg2<<<(NN + 15) / 16, 256, 0, stream>>>(rowptr, csr_src, exs2, hl, bias2, out);
}

// Round 4
// 465.994 us; speedup vs baseline: 4.8537x; 1.1237x over previous
//
#include <hip/hip_runtime.h>
#include <math.h>

// GAT 2-layer, N=50000, E=800000 (+N self loops), IN=128, HID=32, HEADS=4, OUT=32
#define NN   50000
#define EE   800000
#define ETOT 850000          // EE + NN
#define NEG  0.2f

// -------- workspace layout (element offsets, 4B each; ints alias floats) --------
// zero-initialized region (one contiguous memset):
#define O_DEG    0           //    50,000  in-degree per node (int)
#define O_EASUM  50000       //         4  edge_attr sum (scalar)
#define ZERO_ELEMS 50004
// non-zeroed:
#define O_COEF   50004       //         8  coef1[4], coef2 at [4]
#define O_ROWPTR 50012       //    50,001  CSR row pointers (int)
#define O_CURSOR 100016      //    50,000  fill cursors (int)
#define O_CSRSRC 150016      //   850,000  src node per CSR slot (int)
#define O_SLOT   1000016     //   850,000  slot_of_edge (int)
#define O_XL     1850016     // 6,400,000  layer-1 features [N][128]
#define O_ASRC1  8250016     //   200,000  per-node src logits layer1 [N][4]
#define O_ADST1  8450016     //   200,000  per-node dst logits layer1 [N][4]
#define O_EXS1   8650016     // 3,400,000  exp(alpha1) in SLOT order [Etot][4]
#define O_OUT1   12050016    // 6,400,000  layer-1 agg output [N][128]
#define O_ASRC2  18450016    //    50,000  per-node src logits layer2
#define O_ADST2  18500016    //    50,000  per-node dst logits layer2
#define O_HL     O_EXS1      // 1,600,000  layer-2 features (aliases exs1: dead after k_agg1)
#define O_EXS2   O_XL        //   850,000  exp(alpha2) slot order (aliases xl: dead after k_agg1)
#define WS_ELEMS 18550016    // ~74.2 MB

// -------------------- edge_attr mean (sum) --------------------
__global__ void k_ea_reduce(const float* __restrict__ ea, float* __restrict__ easum) {
  __shared__ float red[4];
  float s = 0.f;
  int stride = gridDim.x * blockDim.x;
  for (int i = blockIdx.x * blockDim.x + threadIdx.x; i < EE; i += stride)
    s += ea[i];
  #pragma unroll
  for (int o = 32; o > 0; o >>= 1) s += __shfl_down(s, o, 64);
  if ((threadIdx.x & 63) == 0) red[threadIdx.x >> 6] = s;
  __syncthreads();
  if (threadIdx.x == 0) atomicAdd(easum, red[0] + red[1] + red[2] + red[3]);
}

// -------------------- edge-coef precompute --------------------
__global__ void k_coef(const float* __restrict__ lew1, const float* __restrict__ ae1,
                       const float* __restrict__ lew2, const float* __restrict__ ae2,
                       float* __restrict__ coef) {
  int t = threadIdx.x; // 128 threads
  float p = lew1[t] * ae1[t];
  #pragma unroll
  for (int o = 16; o > 0; o >>= 1) p += __shfl_down(p, o, 32);
  if ((t & 31) == 0) coef[t >> 5] = p;
  if (t < 32) {
    float q = lew2[t] * ae2[t];
    #pragma unroll
    for (int o = 16; o > 0; o >>= 1) q += __shfl_down(q, o, 32);
    if (t == 0) coef[4] = q;
  }
}

// -------------------- CSR build: count, scan, fill --------------------
__global__ void k_count(const int* __restrict__ ei, int* __restrict__ deg) {
  int e = blockIdx.x * 256 + threadIdx.x;
  if (e >= ETOT) return;
  int d = (e < EE) ? ei[EE + e] : e - EE;
  atomicAdd(deg + d, 1);
}

// single block, 1024 threads, 49 elems/thread; exclusive scan of deg -> rowptr, cursor
#define SCAN_CH 49
__global__ __launch_bounds__(1024) void k_scan(const int* __restrict__ deg,
                                               int* __restrict__ rowptr,
                                               int* __restrict__ cursor) {
  __shared__ int part[1024];
  const int t = threadIdx.x;
  const int base = t * SCAN_CH;
  int local[SCAN_CH];
  int s = 0;
  #pragma unroll
  for (int i = 0; i < SCAN_CH; ++i) {
    int idx = base + i;
    int v = (idx < NN) ? deg[idx] : 0;
    local[i] = s;
    s += v;
  }
  part[t] = s;
  __syncthreads();
  for (int o = 1; o < 1024; o <<= 1) {
    int v = (t >= o) ? part[t - o] : 0;
    __syncthreads();
    part[t] += v;
    __syncthreads();
  }
  int off = (t > 0) ? part[t - 1] : 0;
  #pragma unroll
  for (int i = 0; i < SCAN_CH; ++i) {
    int idx = base + i;
    if (idx < NN) {
      int r = off + local[i];
      rowptr[idx] = r;
      cursor[idx] = r;
    }
  }
  if (t == 0) rowptr[NN] = ETOT;
}

__global__ void k_fill(const int* __restrict__ ei, int* __restrict__ cursor,
                       int* __restrict__ csr_src, int* __restrict__ slot_of) {
  int e = blockIdx.x * 256 + threadIdx.x;
  if (e >= ETOT) return;
  int s, d;
  if (e < EE) { s = ei[e]; d = ei[EE + e]; }
  else { s = d = e - EE; }
  int slot = atomicAdd(cursor + d, 1);
  csr_src[slot] = s;
  slot_of[e] = slot;
}

// 32 FMAs against one uniform W row of 32 floats
#define GEMM_STEP(WB, K, XS) {                                              \
    const float4* Wr = (const float4*)((WB) + (size_t)(K));                 \
    _Pragma("unroll")                                                       \
    for (int j4 = 0; j4 < 8; ++j4) {                                        \
      float4 wv = Wr[j4];                                                   \
      acc[j4 * 4 + 0] += (XS) * wv.x;                                       \
      acc[j4 * 4 + 1] += (XS) * wv.y;                                       \
      acc[j4 * 4 + 2] += (XS) * wv.z;                                       \
      acc[j4 * 4 + 3] += (XS) * wv.w;                                       \
    } }

// -------------------- layer-1 GEMM: xl = x @ W1, plus per-node logits --------------------
// 1 wave per block; head from blockIdx (wave-uniform W address -> SMEM-eligible);
// lane = node, reads its own x row from global; NO LDS, no barriers.
__global__ __launch_bounds__(64) void k_lin1(
    const float* __restrict__ x, const float* __restrict__ W,
    const float* __restrict__ att_src, const float* __restrict__ att_dst,
    float* __restrict__ xl, float* __restrict__ asrc, float* __restrict__ adst) {
  const int bid = blockIdx.x;
  const int h   = bid & 3;                    // head (uniform)
  const int n   = (bid >> 2) * 64 + threadIdx.x;
  const int nc  = n < NN ? n : NN - 1;
  const float4* xr = (const float4*)(x + (size_t)nc * 128);
  const float*  Wh = W + h * 32;              // uniform base
  float acc[32];
  #pragma unroll
  for (int j = 0; j < 32; ++j) acc[j] = 0.f;
  float4 xv = xr[0];
  for (int kt = 0; kt < 32; ++kt) {
    float4 cur = xv;
    if (kt < 31) xv = xr[kt + 1];             // prefetch next 16B of x
    GEMM_STEP(Wh, (kt * 4 + 0) * 128, cur.x);
    GEMM_STEP(Wh, (kt * 4 + 1) * 128, cur.y);
    GEMM_STEP(Wh, (kt * 4 + 2) * 128, cur.z);
    GEMM_STEP(Wh, (kt * 4 + 3) * 128, cur.w);
  }
  if (n < NN) {
    #pragma unroll
    for (int j4 = 0; j4 < 8; ++j4) {
      float4 o;
      o.x = acc[j4 * 4 + 0]; o.y = acc[j4 * 4 + 1];
      o.z = acc[j4 * 4 + 2]; o.w = acc[j4 * 4 + 3];
      *(float4*)(xl + (size_t)n * 128 + h * 32 + j4 * 4) = o;
    }
    float ss = 0.f, sd = 0.f;
    #pragma unroll
    for (int j = 0; j < 32; ++j) {
      ss += acc[j] * att_src[h * 32 + j];     // uniform
      sd += acc[j] * att_dst[h * 32 + j];
    }
    asrc[n * 4 + h] = ss;
    adst[n * 4 + h] = sd;
  }
}

// -------------------- layer-1 edge pass: exp(leaky(logits)) scattered to slot order ----
__global__ void k_edge1(const int* __restrict__ ei, const float* __restrict__ eattr,
                        const float* __restrict__ asrc, const float* __restrict__ adst,
                        const float* __restrict__ coef, const float* __restrict__ easum,
                        const int* __restrict__ slot_of, float* __restrict__ exs1) {
  int e = blockIdx.x * 256 + threadIdx.x;
  if (e >= ETOT) return;
  int s, d; float ea;
  if (e < EE) { s = ei[e]; d = ei[EE + e]; ea = eattr[e]; }
  else { s = d = e - EE; ea = easum[0] * (1.f / EE); }   // self-loop, mean attr
  float4 as = *(const float4*)(asrc + (size_t)s * 4);
  float4 ad = *(const float4*)(adst + (size_t)d * 4);
  float4 c = *(const float4*)(coef);
  float a0 = as.x + ad.x + ea * c.x;
  float a1 = as.y + ad.y + ea * c.y;
  float a2 = as.z + ad.z + ea * c.z;
  float a3 = as.w + ad.w + ea * c.w;
  a0 = a0 > 0.f ? a0 : NEG * a0;
  a1 = a1 > 0.f ? a1 : NEG * a1;
  a2 = a2 > 0.f ? a2 : NEG * a2;
  a3 = a3 > 0.f ? a3 : NEG * a3;
  // |alpha| <= ~1 for this data -> exp without max-subtraction is safe
  float4 ex;
  ex.x = expf(a0); ex.y = expf(a1); ex.z = expf(a2); ex.w = expf(a3);
  *(float4*)(exs1 + (size_t)slot_of[e] * 4) = ex;
}

// -------------------- layer-1 aggregation: half-wave per node, float4 per lane -----------
__global__ __launch_bounds__(256) void k_agg1(
    const int* __restrict__ rowptr, const int* __restrict__ csr_src,
    const float* __restrict__ exs1, const float* __restrict__ xl,
    float* __restrict__ out1) {
  int n = blockIdx.x * 8 + (threadIdx.x >> 5);
  if (n >= NN) return;
  int l = threadIdx.x & 31;
  int c4 = l << 2;                    // 4 channels per lane, 32 lanes = 128 ch
  int h = l >> 3;                     // head of this channel group
  int r0 = rowptr[n], r1 = rowptr[n + 1];   // r1 > r0 (self-loop)
  float a0 = 0.f, a1 = 0.f, a2 = 0.f, a3 = 0.f, den = 0.f;
  int s = csr_src[r0];
  float ex = exs1[(size_t)r0 * 4 + h];
  for (int j = r0; j < r1; ++j) {
    int sc = s; float exc = ex;
    if (j + 1 < r1) {                 // half-wave-uniform branch
      s = csr_src[j + 1];
      ex = exs1[(size_t)(j + 1) * 4 + h];
    }
    float4 xv = *(const float4*)(xl + (size_t)sc * 128 + c4);
    a0 += exc * xv.x;
    a1 += exc * xv.y;
    a2 += exc * xv.z;
    a3 += exc * xv.w;
    den += exc;
  }
  float inv = 1.f / den;
  *(float4*)(out1 + (size_t)n * 128 + c4) = make_float4(a0 * inv, a1 * inv, a2 * inv, a3 * inv);
}

// -------------------- layer-2 GEMM: hl = elu(out1+bias1) @ W2, plus logits --------------
// 1 wave per block; lane = node owns all 32 out channels -> logits fully in-lane.
__global__ __launch_bounds__(64) void k_lin2(
    const float* __restrict__ out1, const float* __restrict__ bias1,
    const float* __restrict__ W2,
    const float* __restrict__ as2w, const float* __restrict__ ad2w,
    float* __restrict__ hl, float* __restrict__ asrc2, float* __restrict__ adst2) {
  const int n  = blockIdx.x * 64 + threadIdx.x;
  const int nc = n < NN ? n : NN - 1;
  const float4* xr = (const float4*)(out1 + (size_t)nc * 128);
  const float4* br = (const float4*)bias1;   // uniform
  float acc[32];
  #pragma unroll
  for (int j = 0; j < 32; ++j) acc[j] = 0.f;
  float4 xv = xr[0];
  for (int kt = 0; kt < 32; ++kt) {
    float4 cur = xv;
    if (kt < 31) xv = xr[kt + 1];
    float4 b = br[kt];                       // uniform
    cur.x += b.x; cur.y += b.y; cur.z += b.z; cur.w += b.w;
    cur.x = cur.x > 0.f ? cur.x : (expf(cur.x) - 1.f);   // ELU (once per element)
    cur.y = cur.y > 0.f ? cur.y : (expf(cur.y) - 1.f);
    cur.z = cur.z > 0.f ? cur.z : (expf(cur.z) - 1.f);
    cur.w = cur.w > 0.f ? cur.w : (expf(cur.w) - 1.f);
    GEMM_STEP(W2, (kt * 4 + 0) * 32, cur.x);
    GEMM_STEP(W2, (kt * 4 + 1) * 32, cur.y);
    GEMM_STEP(W2, (kt * 4 + 2) * 32, cur.z);
    GEMM_STEP(W2, (kt * 4 + 3) * 32, cur.w);
  }
  if (n < NN) {
    #pragma unroll
    for (int j4 = 0; j4 < 8; ++j4) {
      float4 o;
      o.x = acc[j4 * 4 + 0]; o.y = acc[j4 * 4 + 1];
      o.z = acc[j4 * 4 + 2]; o.w = acc[j4 * 4 + 3];
      *(float4*)(hl + (size_t)n * 32 + j4 * 4) = o;
    }
    float ps = 0.f, pd = 0.f;
    #pragma unroll
    for (int j = 0; j < 32; ++j) {
      ps += acc[j] * as2w[j];                // uniform
      pd += acc[j] * ad2w[j];
    }
    asrc2[n] = ps;
    adst2[n] = pd;
  }
}

// -------------------- layer-2 edge pass --------------------
__global__ void k_edge2(const int* __restrict__ ei, const float* __restrict__ eattr,
                        const float* __restrict__ as2, const float* __restrict__ ad2,
                        const float* __restrict__ coef, const float* __restrict__ easum,
                        const int* __restrict__ slot_of, float* __restrict__ exs2) {
  int e = blockIdx.x * 256 + threadIdx.x;
  if (e >= ETOT) return;
  int s, d; float ea;
  if (e < EE) { s = ei[e]; d = ei[EE + e]; ea = eattr[e]; }
  else { s = d = e - EE; ea = easum[0] * (1.f / EE); }
  float a = as2[s] + ad2[d] + ea * coef[4];
  a = a > 0.f ? a : NEG * a;
  exs2[slot_of[e]] = expf(a);
}

// -------------------- layer-2 aggregation: 8 lanes x float4 per node, fused bias2 --------
__global__ __launch_bounds__(256) void k_agg2(
    const int* __restrict__ rowptr, const int* __restrict__ csr_src,
    const float* __restrict__ exs2, const float* __restrict__ hl,
    const float* __restrict__ bias2, float* __restrict__ out) {
  int n = blockIdx.x * 32 + (threadIdx.x >> 3);
  if (n >= NN) return;
  int c4 = (threadIdx.x & 7) << 2;
  int r0 = rowptr[n], r1 = rowptr[n + 1];
  float a0 = 0.f, a1 = 0.f, a2 = 0.f, a3 = 0.f, den = 0.f;
  int s = csr_src[r0];
  float ex = exs2[r0];
  for (int j = r0; j < r1; ++j) {
    int sc = s; float exc = ex;
    if (j + 1 < r1) {
      s = csr_src[j + 1];
      ex = exs2[j + 1];
    }
    float4 hv = *(const float4*)(hl + (size_t)sc * 32 + c4);
    a0 += exc * hv.x;
    a1 += exc * hv.y;
    a2 += exc * hv.z;
    a3 += exc * hv.w;
    den += exc;
  }
  float inv = 1.f / den;
  float4 b = *(const float4*)(bias2 + c4);
  *(float4*)(out + (size_t)n * 32 + c4) =
      make_float4(a0 * inv + b.x, a1 * inv + b.y, a2 * inv + b.z, a3 * inv + b.w);
}

extern "C" void kernel_launch(void* const* d_in, const int* in_sizes, int n_in,
                              void* d_out, int out_size, void* d_ws, size_t ws_size,
                              hipStream_t stream) {
  const float* x        = (const float*)d_in[0];
  const int*   ei       = (const int*)d_in[1];
  const float* eattr    = (const float*)d_in[2];
  const float* lin1_w   = (const float*)d_in[3];
  const float* att1_src = (const float*)d_in[4];
  const float* att1_dst = (const float*)d_in[5];
  const float* lin1_ew  = (const float*)d_in[6];
  const float* att1_e   = (const float*)d_in[7];
  const float* bias1    = (const float*)d_in[8];
  const float* lin2_w   = (const float*)d_in[9];
  const float* att2_src = (const float*)d_in[10];
  const float* att2_dst = (const float*)d_in[11];
  const float* lin2_ew  = (const float*)d_in[12];
  const float* att2_e   = (const float*)d_in[13];
  const float* bias2    = (const float*)d_in[14];
  float* out = (float*)d_out;
  float* ws  = (float*)d_ws;
  int*   wsi = (int*)d_ws;

  int*   deg     = wsi + O_DEG;
  float* easum   = ws + O_EASUM;
  float* coef    = ws + O_COEF;
  int*   rowptr  = wsi + O_ROWPTR;
  int*   cursor  = wsi + O_CURSOR;
  int*   csr_src = wsi + O_CSRSRC;
  int*   slot_of = wsi + O_SLOT;
  float* xl      = ws + O_XL;
  float* asrc1   = ws + O_ASRC1;
  float* adst1   = ws + O_ADST1;
  float* exs1    = ws + O_EXS1;
  float* out1    = ws + O_OUT1;
  float* asrc2   = ws + O_ASRC2;
  float* adst2   = ws + O_ADST2;
  float* hl      = ws + O_HL;    // aliases exs1 (dead after k_agg1)
  float* exs2    = ws + O_EXS2;  // aliases xl   (dead after k_agg1)

  // zero deg/easum (ws poisoned 0xAA each call)
  hipMemsetAsync(ws, 0, (size_t)ZERO_ELEMS * sizeof(float), stream);

  k_ea_reduce<<<256, 256, 0, stream>>>(eattr, easum);
  k_coef<<<1, 128, 0, stream>>>(lin1_ew, att1_e, lin2_ew, att2_e, coef);

  // CSR build (dst-sorted)
  k_count<<<(ETOT + 255) / 256, 256, 0, stream>>>(ei, deg);
  k_scan<<<1, 1024, 0, stream>>>(deg, rowptr, cursor);
  k_fill<<<(ETOT + 255) / 256, 256, 0, stream>>>(ei, cursor, csr_src, slot_of);

  // layer 1
  k_lin1<<<((NN + 63) / 64) * 4, 64, 0, stream>>>(x, lin1_w, att1_src, att1_dst, xl, asrc1, adst1);
  k_edge1<<<(ETOT + 255) / 256, 256, 0, stream>>>(ei, eattr, asrc1, adst1, coef, easum, slot_of, exs1);
  k_agg1<<<(NN + 7) / 8, 256, 0, stream>>>(rowptr, csr_src, exs1, xl, out1);

  // layer 2
  k_lin2<<<(NN + 63) / 64, 64, 0, stream>>>(out1, bias1, lin2_w, att2_src, att2_dst, hl, asrc2, adst2);
  k_edge2<<<(ETOT + 255) / 256, 256, 0, stream>>>(ei, eattr, asrc2, adst2, coef, easum, slot_of, exs2);
  k_agg2<<<(NN + 31) / 32, 256, 0, stream>>>(rowptr, csr_src, exs2, hl, bias2, out);
}

// Round 5
// 381.437 us; speedup vs baseline: 5.9297x; 1.2217x over previous
//
#include <hip/hip_runtime.h>
#include <math.h>

// GAT 2-layer, N=50000, E=800000 (+N self loops), IN=128, HID=32, HEADS=4, OUT=32
#define NN   50000
#define EE   800000
#define ETOT 850000          // EE + NN
#define NEG  0.2f
#define SCAN_BLOCKS ((NN + 255) / 256)   // 196

// -------- workspace layout (element offsets, 4B each; ints alias floats) --------
// zero-initialized region (one contiguous memset):
#define O_DEG    0           //    50,000  in-degree per node (int, EXCLUDING self-loop)
#define O_EASUM  50000       //         4  edge_attr sum (scalar)
#define ZERO_ELEMS 50004
// non-zeroed:
#define O_COEF   50004       //         8  coef1[4], coef2 at [4]
#define O_ROWPTR 50012       //    50,001  CSR row pointers (int)
#define O_CURSOR 100016      //    50,000  fill cursors (int)
#define O_BLKSUM 150016      //       256  per-block scan totals (int)
#define O_BLKOFF 150272      //       256  per-block scan offsets (int)
#define O_CSRSRC 150528      //   850,000  src node per CSR slot (int)
#define O_SLOT   1000528     //   850,000  slot_of_edge (int)
#define O_XL     1850528     // 6,400,000  layer-1 features [N][128]
#define O_ASRC1  8250528     //   200,000  per-node src logits layer1 [N][4]
#define O_ADST1  8450528     //   200,000  per-node dst logits layer1 [N][4]
#define O_EXS1   8650528     // 3,400,000  exp(alpha1) in SLOT order [Etot][4]
#define O_OUT1   12050528    // 6,400,000  layer-1 agg output [N][128]
#define O_ASRC2  18450528    //    50,000  per-node src logits layer2
#define O_ADST2  18500528    //    50,000  per-node dst logits layer2
#define O_HL     O_EXS1      // 1,600,000  layer-2 features (aliases exs1: dead after k_agg1)
#define O_EXS2   O_XL        //   850,000  exp(alpha2) slot order (aliases xl: dead after k_agg1)
#define WS_ELEMS 18550528    // ~74.2 MB

// -------------------- fused: edge_attr sum + degree count (real edges only) -----------
// self-loop degree contribution folded into k_scan_blk (+1 per node).
__global__ void k_ea_count(const float* __restrict__ ea, const int* __restrict__ ei,
                           float* __restrict__ easum, int* __restrict__ deg) {
  __shared__ float red[4];
  float s = 0.f;
  int stride = gridDim.x * blockDim.x;
  for (int i = blockIdx.x * blockDim.x + threadIdx.x; i < EE; i += stride) {
    s += ea[i];
    atomicAdd(deg + ei[EE + i], 1);
  }
  #pragma unroll
  for (int o = 32; o > 0; o >>= 1) s += __shfl_down(s, o, 64);
  if ((threadIdx.x & 63) == 0) red[threadIdx.x >> 6] = s;
  __syncthreads();
  if (threadIdx.x == 0) atomicAdd(easum, red[0] + red[1] + red[2] + red[3]);
}

// -------------------- edge-coef precompute --------------------
__global__ void k_coef(const float* __restrict__ lew1, const float* __restrict__ ae1,
                       const float* __restrict__ lew2, const float* __restrict__ ae2,
                       float* __restrict__ coef) {
  int t = threadIdx.x; // 128 threads
  float p = lew1[t] * ae1[t];
  #pragma unroll
  for (int o = 16; o > 0; o >>= 1) p += __shfl_down(p, o, 32);
  if ((t & 31) == 0) coef[t >> 5] = p;
  if (t < 32) {
    float q = lew2[t] * ae2[t];
    #pragma unroll
    for (int o = 16; o > 0; o >>= 1) q += __shfl_down(q, o, 32);
    if (t == 0) coef[4] = q;
  }
}

// -------------------- multi-block exclusive scan of (deg+1) --------------------
__device__ __forceinline__ int wave_incl_scan(int v, int lane) {
  #pragma unroll
  for (int o = 1; o < 64; o <<= 1) {
    int u = __shfl_up(v, o, 64);
    if (lane >= o) v += u;
  }
  return v;
}

// phase 1: per-block local exclusive scan -> rowptr, block total -> blksum
__global__ __launch_bounds__(256) void k_scan_blk(const int* __restrict__ deg,
                                                  int* __restrict__ rowptr,
                                                  int* __restrict__ blksum) {
  __shared__ int wsum[4];
  const int t = threadIdx.x;
  const int i = blockIdx.x * 256 + t;
  const int lane = t & 63, wv = t >> 6;
  int v = (i < NN) ? (deg[i] + 1) : 0;       // +1 = self-loop
  int incl = wave_incl_scan(v, lane);
  if (lane == 63) wsum[wv] = incl;
  __syncthreads();
  int off = 0;
  #pragma unroll
  for (int k = 0; k < 4; ++k) if (k < wv) off += wsum[k];
  incl += off;
  if (i < NN) rowptr[i] = incl - v;          // local exclusive
  if (t == 255) blksum[blockIdx.x] = incl;   // block total
}

// phase 2: single small block scans the 196 block totals -> blkoff (exclusive)
__global__ __launch_bounds__(256) void k_scan_top(const int* __restrict__ blksum,
                                                  int* __restrict__ blkoff) {
  __shared__ int wsum[4];
  const int t = threadIdx.x;
  const int lane = t & 63, wv = t >> 6;
  int v = (t < SCAN_BLOCKS) ? blksum[t] : 0;
  int incl = wave_incl_scan(v, lane);
  if (lane == 63) wsum[wv] = incl;
  __syncthreads();
  int off = 0;
  #pragma unroll
  for (int k = 0; k < 4; ++k) if (k < wv) off += wsum[k];
  incl += off;
  if (t < SCAN_BLOCKS) blkoff[t] = incl - v;
}

// phase 3: add block offsets; mirror to cursor; rowptr[NN]=ETOT
__global__ __launch_bounds__(256) void k_scan_add(int* __restrict__ rowptr,
                                                  int* __restrict__ cursor,
                                                  const int* __restrict__ blkoff) {
  const int i = blockIdx.x * 256 + threadIdx.x;
  if (i < NN) {
    int r = rowptr[i] + blkoff[blockIdx.x];
    rowptr[i] = r;
    cursor[i] = r;
  }
  if (i == 0) rowptr[NN] = ETOT;
}

__global__ void k_fill(const int* __restrict__ ei, int* __restrict__ cursor,
                       int* __restrict__ csr_src, int* __restrict__ slot_of) {
  int e = blockIdx.x * 256 + threadIdx.x;
  if (e >= ETOT) return;
  int s, d;
  if (e < EE) { s = ei[e]; d = ei[EE + e]; }
  else { s = d = e - EE; }
  int slot = atomicAdd(cursor + d, 1);
  csr_src[slot] = s;
  slot_of[e] = slot;
}

// 32 FMAs against one uniform W row of 32 floats
#define GEMM_STEP(WB, K, XS) {                                              \
    const float4* Wr = (const float4*)((WB) + (size_t)(K));                 \
    _Pragma("unroll")                                                       \
    for (int j4 = 0; j4 < 8; ++j4) {                                        \
      float4 wv = Wr[j4];                                                   \
      acc[j4 * 4 + 0] += (XS) * wv.x;                                       \
      acc[j4 * 4 + 1] += (XS) * wv.y;                                       \
      acc[j4 * 4 + 2] += (XS) * wv.z;                                       \
      acc[j4 * 4 + 3] += (XS) * wv.w;                                       \
    } }

// -------------------- layer-1 GEMM: xl = x @ W1, plus per-node logits --------------------
// 1 wave per block; head from blockIdx (wave-uniform W address -> SMEM-eligible);
// lane = node, reads its own x row from global; NO LDS, no barriers.
__global__ __launch_bounds__(64) void k_lin1(
    const float* __restrict__ x, const float* __restrict__ W,
    const float* __restrict__ att_src, const float* __restrict__ att_dst,
    float* __restrict__ xl, float* __restrict__ asrc, float* __restrict__ adst) {
  const int bid = blockIdx.x;
  const int h   = bid & 3;                    // head (uniform)
  const int n   = (bid >> 2) * 64 + threadIdx.x;
  const int nc  = n < NN ? n : NN - 1;
  const float4* xr = (const float4*)(x + (size_t)nc * 128);
  const float*  Wh = W + h * 32;              // uniform base
  float acc[32];
  #pragma unroll
  for (int j = 0; j < 32; ++j) acc[j] = 0.f;
  float4 xv = xr[0];
  for (int kt = 0; kt < 32; ++kt) {
    float4 cur = xv;
    if (kt < 31) xv = xr[kt + 1];             // prefetch next 16B of x
    GEMM_STEP(Wh, (kt * 4 + 0) * 128, cur.x);
    GEMM_STEP(Wh, (kt * 4 + 1) * 128, cur.y);
    GEMM_STEP(Wh, (kt * 4 + 2) * 128, cur.z);
    GEMM_STEP(Wh, (kt * 4 + 3) * 128, cur.w);
  }
  if (n < NN) {
    #pragma unroll
    for (int j4 = 0; j4 < 8; ++j4) {
      float4 o;
      o.x = acc[j4 * 4 + 0]; o.y = acc[j4 * 4 + 1];
      o.z = acc[j4 * 4 + 2]; o.w = acc[j4 * 4 + 3];
      *(float4*)(xl + (size_t)n * 128 + h * 32 + j4 * 4) = o;
    }
    float ss = 0.f, sd = 0.f;
    #pragma unroll
    for (int j = 0; j < 32; ++j) {
      ss += acc[j] * att_src[h * 32 + j];     // uniform
      sd += acc[j] * att_dst[h * 32 + j];
    }
    asrc[n * 4 + h] = ss;
    adst[n * 4 + h] = sd;
  }
}

// -------------------- layer-1 edge pass: exp(leaky(logits)) scattered to slot order ----
__global__ void k_edge1(const int* __restrict__ ei, const float* __restrict__ eattr,
                        const float* __restrict__ asrc, const float* __restrict__ adst,
                        const float* __restrict__ coef, const float* __restrict__ easum,
                        const int* __restrict__ slot_of, float* __restrict__ exs1) {
  int e = blockIdx.x * 256 + threadIdx.x;
  if (e >= ETOT) return;
  int s, d; float ea;
  if (e < EE) { s = ei[e]; d = ei[EE + e]; ea = eattr[e]; }
  else { s = d = e - EE; ea = easum[0] * (1.f / EE); }   // self-loop, mean attr
  float4 as = *(const float4*)(asrc + (size_t)s * 4);
  float4 ad = *(const float4*)(adst + (size_t)d * 4);
  float4 c = *(const float4*)(coef);
  float a0 = as.x + ad.x + ea * c.x;
  float a1 = as.y + ad.y + ea * c.y;
  float a2 = as.z + ad.z + ea * c.z;
  float a3 = as.w + ad.w + ea * c.w;
  a0 = a0 > 0.f ? a0 : NEG * a0;
  a1 = a1 > 0.f ? a1 : NEG * a1;
  a2 = a2 > 0.f ? a2 : NEG * a2;
  a3 = a3 > 0.f ? a3 : NEG * a3;
  // |alpha| <= ~1 for this data -> exp without max-subtraction is safe
  float4 ex;
  ex.x = expf(a0); ex.y = expf(a1); ex.z = expf(a2); ex.w = expf(a3);
  *(float4*)(exs1 + (size_t)slot_of[e] * 4) = ex;
}

// -------------------- layer-1 aggregation: half-wave per node, float4 per lane -----------
__global__ __launch_bounds__(256) void k_agg1(
    const int* __restrict__ rowptr, const int* __restrict__ csr_src,
    const float* __restrict__ exs1, const float* __restrict__ xl,
    float* __restrict__ out1) {
  int n = blockIdx.x * 8 + (threadIdx.x >> 5);
  if (n >= NN) return;
  int l = threadIdx.x & 31;
  int c4 = l << 2;                    // 4 channels per lane, 32 lanes = 128 ch
  int h = l >> 3;                     // head of this channel group
  int r0 = rowptr[n], r1 = rowptr[n + 1];   // r1 > r0 (self-loop)
  float a0 = 0.f, a1 = 0.f, a2 = 0.f, a3 = 0.f, den = 0.f;
  int s = csr_src[r0];
  float ex = exs1[(size_t)r0 * 4 + h];
  for (int j = r0; j < r1; ++j) {
    int sc = s; float exc = ex;
    if (j + 1 < r1) {                 // half-wave-uniform branch
      s = csr_src[j + 1];
      ex = exs1[(size_t)(j + 1) * 4 + h];
    }
    float4 xv = *(const float4*)(xl + (size_t)sc * 128 + c4);
    a0 += exc * xv.x;
    a1 += exc * xv.y;
    a2 += exc * xv.z;
    a3 += exc * xv.w;
    den += exc;
  }
  float inv = 1.f / den;
  *(float4*)(out1 + (size_t)n * 128 + c4) = make_float4(a0 * inv, a1 * inv, a2 * inv, a3 * inv);
}

// -------------------- layer-2 GEMM: hl = elu(out1+bias1) @ W2, plus logits --------------
// 1 wave per block; lane = node owns all 32 out channels -> logits fully in-lane.
__global__ __launch_bounds__(64) void k_lin2(
    const float* __restrict__ out1, const float* __restrict__ bias1,
    const float* __restrict__ W2,
    const float* __restrict__ as2w, const float* __restrict__ ad2w,
    float* __restrict__ hl, float* __restrict__ asrc2, float* __restrict__ adst2) {
  const int n  = blockIdx.x * 64 + threadIdx.x;
  const int nc = n < NN ? n : NN - 1;
  const float4* xr = (const float4*)(out1 + (size_t)nc * 128);
  const float4* br = (const float4*)bias1;   // uniform
  float acc[32];
  #pragma unroll
  for (int j = 0; j < 32; ++j) acc[j] = 0.f;
  float4 xv = xr[0];
  for (int kt = 0; kt < 32; ++kt) {
    float4 cur = xv;
    if (kt < 31) xv = xr[kt + 1];
    float4 b = br[kt];                       // uniform
    cur.x += b.x; cur.y += b.y; cur.z += b.z; cur.w += b.w;
    cur.x = cur.x > 0.f ? cur.x : (expf(cur.x) - 1.f);   // ELU (once per element)
    cur.y = cur.y > 0.f ? cur.y : (expf(cur.y) - 1.f);
    cur.z = cur.z > 0.f ? cur.z : (expf(cur.z) - 1.f);
    cur.w = cur.w > 0.f ? cur.w : (expf(cur.w) - 1.f);
    GEMM_STEP(W2, (kt * 4 + 0) * 32, cur.x);
    GEMM_STEP(W2, (kt * 4 + 1) * 32, cur.y);
    GEMM_STEP(W2, (kt * 4 + 2) * 32, cur.z);
    GEMM_STEP(W2, (kt * 4 + 3) * 32, cur.w);
  }
  if (n < NN) {
    #pragma unroll
    for (int j4 = 0; j4 < 8; ++j4) {
      float4 o;
      o.x = acc[j4 * 4 + 0]; o.y = acc[j4 * 4 + 1];
      o.z = acc[j4 * 4 + 2]; o.w = acc[j4 * 4 + 3];
      *(float4*)(hl + (size_t)n * 32 + j4 * 4) = o;
    }
    float ps = 0.f, pd = 0.f;
    #pragma unroll
    for (int j = 0; j < 32; ++j) {
      ps += acc[j] * as2w[j];                // uniform
      pd += acc[j] * ad2w[j];
    }
    asrc2[n] = ps;
    adst2[n] = pd;
  }
}

// -------------------- layer-2 edge pass --------------------
__global__ void k_edge2(const int* __restrict__ ei, const float* __restrict__ eattr,
                        const float* __restrict__ as2, const float* __restrict__ ad2,
                        const float* __restrict__ coef, const float* __restrict__ easum,
                        const int* __restrict__ slot_of, float* __restrict__ exs2) {
  int e = blockIdx.x * 256 + threadIdx.x;
  if (e >= ETOT) return;
  int s, d; float ea;
  if (e < EE) { s = ei[e]; d = ei[EE + e]; ea = eattr[e]; }
  else { s = d = e - EE; ea = easum[0] * (1.f / EE); }
  float a = as2[s] + ad2[d] + ea * coef[4];
  a = a > 0.f ? a : NEG * a;
  exs2[slot_of[e]] = expf(a);
}

// -------------------- layer-2 aggregation: 8 lanes x float4 per node, fused bias2 --------
__global__ __launch_bounds__(256) void k_agg2(
    const int* __restrict__ rowptr, const int* __restrict__ csr_src,
    const float* __restrict__ exs2, const float* __restrict__ hl,
    const float* __restrict__ bias2, float* __restrict__ out) {
  int n = blockIdx.x * 32 + (threadIdx.x >> 3);
  if (n >= NN) return;
  int c4 = (threadIdx.x & 7) << 2;
  int r0 = rowptr[n], r1 = rowptr[n + 1];
  float a0 = 0.f, a1 = 0.f, a2 = 0.f, a3 = 0.f, den = 0.f;
  int s = csr_src[r0];
  float ex = exs2[r0];
  for (int j = r0; j < r1; ++j) {
    int sc = s; float exc = ex;
    if (j + 1 < r1) {
      s = csr_src[j + 1];
      ex = exs2[j + 1];
    }
    float4 hv = *(const float4*)(hl + (size_t)sc * 32 + c4);
    a0 += exc * hv.x;
    a1 += exc * hv.y;
    a2 += exc * hv.z;
    a3 += exc * hv.w;
    den += exc;
  }
  float inv = 1.f / den;
  float4 b = *(const float4*)(bias2 + c4);
  *(float4*)(out + (size_t)n * 32 + c4) =
      make_float4(a0 * inv + b.x, a1 * inv + b.y, a2 * inv + b.z, a3 * inv + b.w);
}

extern "C" void kernel_launch(void* const* d_in, const int* in_sizes, int n_in,
                              void* d_out, int out_size, void* d_ws, size_t ws_size,
                              hipStream_t stream) {
  const float* x        = (const float*)d_in[0];
  const int*   ei       = (const int*)d_in[1];
  const float* eattr    = (const float*)d_in[2];
  const float* lin1_w   = (const float*)d_in[3];
  const float* att1_src = (const float*)d_in[4];
  const float* att1_dst = (const float*)d_in[5];
  const float* lin1_ew  = (const float*)d_in[6];
  const float* att1_e   = (const float*)d_in[7];
  const float* bias1    = (const float*)d_in[8];
  const float* lin2_w   = (const float*)d_in[9];
  const float* att2_src = (const float*)d_in[10];
  const float* att2_dst = (const float*)d_in[11];
  const float* lin2_ew  = (const float*)d_in[12];
  const float* att2_e   = (const float*)d_in[13];
  const float* bias2    = (const float*)d_in[14];
  float* out = (float*)d_out;
  float* ws  = (float*)d_ws;
  int*   wsi = (int*)d_ws;

  int*   deg     = wsi + O_DEG;
  float* easum   = ws + O_EASUM;
  float* coef    = ws + O_COEF;
  int*   rowptr  = wsi + O_ROWPTR;
  int*   cursor  = wsi + O_CURSOR;
  int*   blksum  = wsi + O_BLKSUM;
  int*   blkoff  = wsi + O_BLKOFF;
  int*   csr_src = wsi + O_CSRSRC;
  int*   slot_of = wsi + O_SLOT;
  float* xl      = ws + O_XL;
  float* asrc1   = ws + O_ASRC1;
  float* adst1   = ws + O_ADST1;
  float* exs1    = ws + O_EXS1;
  float* out1    = ws + O_OUT1;
  float* asrc2   = ws + O_ASRC2;
  float* adst2   = ws + O_ADST2;
  float* hl      = ws + O_HL;    // aliases exs1 (dead after k_agg1)
  float* exs2    = ws + O_EXS2;  // aliases xl   (dead after k_agg1)

  // zero deg/easum (ws poisoned 0xAA each call)
  hipMemsetAsync(ws, 0, (size_t)ZERO_ELEMS * sizeof(float), stream);

  k_ea_count<<<256, 256, 0, stream>>>(eattr, ei, easum, deg);
  k_coef<<<1, 128, 0, stream>>>(lin1_ew, att1_e, lin2_ew, att2_e, coef);

  // CSR build (dst-sorted): multi-block scan
  k_scan_blk<<<SCAN_BLOCKS, 256, 0, stream>>>(deg, rowptr, blksum);
  k_scan_top<<<1, 256, 0, stream>>>(blksum, blkoff);
  k_scan_add<<<SCAN_BLOCKS, 256, 0, stream>>>(rowptr, cursor, blkoff);
  k_fill<<<(ETOT + 255) / 256, 256, 0, stream>>>(ei, cursor, csr_src, slot_of);

  // layer 1
  k_lin1<<<((NN + 63) / 64) * 4, 64, 0, stream>>>(x, lin1_w, att1_src, att1_dst, xl, asrc1, adst1);
  k_edge1<<<(ETOT + 255) / 256, 256, 0, stream>>>(ei, eattr, asrc1, adst1, coef, easum, slot_of, exs1);
  k_agg1<<<(NN + 7) / 8, 256, 0, stream>>>(rowptr, csr_src, exs1, xl, out1);

  // layer 2
  k_lin2<<<(NN + 63) / 64, 64, 0, stream>>>(out1, bias1, lin2_w, att2_src, att2_dst, hl, asrc2, adst2);
  k_edge2<<<(ETOT + 255) / 256, 256, 0, stream>>>(ei, eattr, asrc2, adst2, coef, easum, slot_of, exs2);
  k_agg2<<<(NN + 31) / 32, 256, 0, stream>>>(rowptr, csr_src, exs2, hl, bias2, out);
}

// Round 6
// 346.636 us; speedup vs baseline: 6.5250x; 1.1004x over previous
//
#include <hip/hip_runtime.h>
#include <hip/hip_fp16.h>
#include <math.h>

// GAT 2-layer, N=50000, E=800000 (+N self loops), IN=128, HID=32, HEADS=4, OUT=32
#define NN   50000
#define EE   800000
#define ETOT 850000          // EE + NN
#define NEG  0.2f
#define SCAN_BLOCKS ((NN + 255) / 256)   // 196

// -------- workspace layout (element offsets, 4B units; ints/halfs alias floats) --------
// zero-initialized region (one contiguous memset):
#define O_DEG    0           //    50,000  in-degree per node (int, EXCLUDING self-loop)
#define O_EASUM  50000       //         4  edge_attr sum (scalar)
#define ZERO_ELEMS 50004
// non-zeroed:
#define O_COEF   50004       //         8  coef1[4], coef2 at [4]
#define O_ROWPTR 50012       //    50,001  CSR row pointers (int)
#define O_CURSOR 100016      //    50,000  fill cursors (int)
#define O_BLKSUM 150016      //       256  per-block scan totals (int)
#define O_BLKOFF 150272      //       256  per-block scan offsets (int)
#define O_CSRSRC 150528      //   850,000  src node per CSR slot (int)
#define O_EASLOT 1000528     //   850,000  edge attr in CSR slot order (float)
#define O_ASRC1  1850528     //   200,000  per-node src logits layer1 [N][4]
#define O_ADST1  2050528     //   200,000  per-node dst logits layer1 [N][4]
#define O_XLH    2250528     // 3,200,000  layer-1 features fp16 [N][128] (6.4M halfs)
#define O_OUT1   5450528     // 6,400,000  layer-1 agg output fp32 [N][128]
#define O_HLH    11850528    //   800,000  layer-2 features fp16 [N][32] (1.6M halfs)
#define O_ASRC2  12650528    //    50,000  per-node src logits layer2
#define O_ADST2  12700528    //    50,000  per-node dst logits layer2
#define WS_ELEMS 12750528    // ~51 MB

// -------------------- fused: edge_attr sum + degree count (real edges only) -----------
__global__ void k_ea_count(const float* __restrict__ ea, const int* __restrict__ ei,
                           float* __restrict__ easum, int* __restrict__ deg) {
  __shared__ float red[4];
  float s = 0.f;
  int stride = gridDim.x * blockDim.x;
  for (int i = blockIdx.x * blockDim.x + threadIdx.x; i < EE; i += stride) {
    s += ea[i];
    atomicAdd(deg + ei[EE + i], 1);
  }
  #pragma unroll
  for (int o = 32; o > 0; o >>= 1) s += __shfl_down(s, o, 64);
  if ((threadIdx.x & 63) == 0) red[threadIdx.x >> 6] = s;
  __syncthreads();
  if (threadIdx.x == 0) atomicAdd(easum, red[0] + red[1] + red[2] + red[3]);
}

// -------------------- edge-coef precompute --------------------
__global__ void k_coef(const float* __restrict__ lew1, const float* __restrict__ ae1,
                       const float* __restrict__ lew2, const float* __restrict__ ae2,
                       float* __restrict__ coef) {
  int t = threadIdx.x; // 128 threads
  float p = lew1[t] * ae1[t];
  #pragma unroll
  for (int o = 16; o > 0; o >>= 1) p += __shfl_down(p, o, 32);
  if ((t & 31) == 0) coef[t >> 5] = p;
  if (t < 32) {
    float q = lew2[t] * ae2[t];
    #pragma unroll
    for (int o = 16; o > 0; o >>= 1) q += __shfl_down(q, o, 32);
    if (t == 0) coef[4] = q;
  }
}

// -------------------- multi-block exclusive scan of (deg+1) --------------------
__device__ __forceinline__ int wave_incl_scan(int v, int lane) {
  #pragma unroll
  for (int o = 1; o < 64; o <<= 1) {
    int u = __shfl_up(v, o, 64);
    if (lane >= o) v += u;
  }
  return v;
}

__global__ __launch_bounds__(256) void k_scan_blk(const int* __restrict__ deg,
                                                  int* __restrict__ rowptr,
                                                  int* __restrict__ blksum) {
  __shared__ int wsum[4];
  const int t = threadIdx.x;
  const int i = blockIdx.x * 256 + t;
  const int lane = t & 63, wv = t >> 6;
  int v = (i < NN) ? (deg[i] + 1) : 0;       // +1 = self-loop
  int incl = wave_incl_scan(v, lane);
  if (lane == 63) wsum[wv] = incl;
  __syncthreads();
  int off = 0;
  #pragma unroll
  for (int k = 0; k < 4; ++k) if (k < wv) off += wsum[k];
  incl += off;
  if (i < NN) rowptr[i] = incl - v;          // local exclusive
  if (t == 255) blksum[blockIdx.x] = incl;   // block total
}

__global__ __launch_bounds__(256) void k_scan_top(const int* __restrict__ blksum,
                                                  int* __restrict__ blkoff) {
  __shared__ int wsum[4];
  const int t = threadIdx.x;
  const int lane = t & 63, wv = t >> 6;
  int v = (t < SCAN_BLOCKS) ? blksum[t] : 0;
  int incl = wave_incl_scan(v, lane);
  if (lane == 63) wsum[wv] = incl;
  __syncthreads();
  int off = 0;
  #pragma unroll
  for (int k = 0; k < 4; ++k) if (k < wv) off += wsum[k];
  incl += off;
  if (t < SCAN_BLOCKS) blkoff[t] = incl - v;
}

__global__ __launch_bounds__(256) void k_scan_add(int* __restrict__ rowptr,
                                                  int* __restrict__ cursor,
                                                  const int* __restrict__ blkoff) {
  const int i = blockIdx.x * 256 + threadIdx.x;
  if (i < NN) {
    int r = rowptr[i] + blkoff[blockIdx.x];
    rowptr[i] = r;
    cursor[i] = r;
  }
  if (i == 0) rowptr[NN] = ETOT;
}

// fill CSR src + edge attr in slot order (self-loop attr = mean)
__global__ void k_fill(const int* __restrict__ ei, const float* __restrict__ eattr,
                       const float* __restrict__ easum, int* __restrict__ cursor,
                       int* __restrict__ csr_src, float* __restrict__ ea_slot) {
  int e = blockIdx.x * 256 + threadIdx.x;
  if (e >= ETOT) return;
  int s, d; float ea;
  if (e < EE) { s = ei[e]; d = ei[EE + e]; ea = eattr[e]; }
  else { s = d = e - EE; ea = easum[0] * (1.f / EE); }
  int slot = atomicAdd(cursor + d, 1);
  csr_src[slot] = s;
  ea_slot[slot] = ea;
}

// 32 FMAs against one uniform W row of 32 floats
#define GEMM_STEP(WB, K, XS) {                                              \
    const float4* Wr = (const float4*)((WB) + (size_t)(K));                 \
    _Pragma("unroll")                                                       \
    for (int j4 = 0; j4 < 8; ++j4) {                                        \
      float4 wv = Wr[j4];                                                   \
      acc[j4 * 4 + 0] += (XS) * wv.x;                                       \
      acc[j4 * 4 + 1] += (XS) * wv.y;                                       \
      acc[j4 * 4 + 2] += (XS) * wv.z;                                       \
      acc[j4 * 4 + 3] += (XS) * wv.w;                                       \
    } }

// -------------------- layer-1 GEMM: xl(fp16) = x @ W1, plus per-node logits -------------
// 1 wave per block; head varies SLOWEST across grid (x re-reads hit L3);
// lane = node; wave-uniform W -> scalar loads; NO LDS, no barriers.
#define L1_NB ((NN + 63) / 64)      // 782 node-blocks per head
__global__ __launch_bounds__(64) void k_lin1(
    const float* __restrict__ x, const float* __restrict__ W,
    const float* __restrict__ att_src, const float* __restrict__ att_dst,
    __half* __restrict__ xlh, float* __restrict__ asrc, float* __restrict__ adst) {
  const int bid = blockIdx.x;
  const int h   = bid / L1_NB;                // head (uniform, slowest)
  const int n   = (bid % L1_NB) * 64 + threadIdx.x;
  const int nc  = n < NN ? n : NN - 1;
  const float4* xr = (const float4*)(x + (size_t)nc * 128);
  const float*  Wh = W + h * 32;              // uniform base
  float acc[32];
  #pragma unroll
  for (int j = 0; j < 32; ++j) acc[j] = 0.f;
  float4 xv = xr[0];
  for (int kt = 0; kt < 32; ++kt) {
    float4 cur = xv;
    if (kt < 31) xv = xr[kt + 1];             // prefetch next 16B of x
    GEMM_STEP(Wh, (kt * 4 + 0) * 128, cur.x);
    GEMM_STEP(Wh, (kt * 4 + 1) * 128, cur.y);
    GEMM_STEP(Wh, (kt * 4 + 2) * 128, cur.z);
    GEMM_STEP(Wh, (kt * 4 + 3) * 128, cur.w);
  }
  if (n < NN) {
    __align__(16) __half hbuf[32];
    #pragma unroll
    for (int j = 0; j < 32; ++j) hbuf[j] = __float2half_rn(acc[j]);
    float4* dst = (float4*)(xlh + (size_t)n * 128 + h * 32);   // 64 B, 16B-aligned
    #pragma unroll
    for (int i = 0; i < 4; ++i) dst[i] = ((const float4*)hbuf)[i];
    float ss = 0.f, sd = 0.f;
    #pragma unroll
    for (int j = 0; j < 32; ++j) {
      ss += acc[j] * att_src[h * 32 + j];     // uniform
      sd += acc[j] * att_dst[h * 32 + j];
    }
    asrc[n * 4 + h] = ss;
    adst[n * 4 + h] = sd;
  }
}

// -------------------- layer-1 aggregation (fused softmax): half-wave per node ------------
// ex computed in-register from asrc/adst/ea_slot; xl gathered as fp16 (8B/lane).
__global__ __launch_bounds__(256) void k_agg1(
    const int* __restrict__ rowptr, const int* __restrict__ csr_src,
    const float* __restrict__ ea_slot, const float* __restrict__ asrc,
    const float* __restrict__ adst, const float* __restrict__ coef,
    const __half* __restrict__ xlh, float* __restrict__ out1) {
  int n = blockIdx.x * 8 + (threadIdx.x >> 5);
  if (n >= NN) return;
  int l = threadIdx.x & 31;
  int c4 = l << 2;                    // 4 channels per lane, 32 lanes = 128 ch
  int h = l >> 3;                     // head of this channel group
  float cf = coef[h];
  float ad = adst[(size_t)n * 4 + h];
  int r0 = rowptr[n], r1 = rowptr[n + 1];   // r1 > r0 (self-loop)
  float a0 = 0.f, a1 = 0.f, a2 = 0.f, a3 = 0.f, den = 0.f;
  int s = csr_src[r0];
  float ea = ea_slot[r0];
  float as = asrc[(size_t)s * 4 + h];
  for (int j = r0; j < r1; ++j) {
    int sc = s; float eac = ea; float asc = as;
    if (j + 1 < r1) {                 // half-wave-uniform branch
      s = csr_src[j + 1];
      ea = ea_slot[j + 1];
      as = asrc[(size_t)s * 4 + h];
    }
    uint2 raw = *(const uint2*)(xlh + (size_t)sc * 128 + c4);   // 4 halfs
    float alpha = asc + ad + eac * cf;
    alpha = alpha > 0.f ? alpha : NEG * alpha;
    float ex = __expf(alpha);
    __half2 p0, p1;
    *(unsigned int*)&p0 = raw.x;
    *(unsigned int*)&p1 = raw.y;
    float2 f0 = __half22float2(p0), f1 = __half22float2(p1);
    a0 += ex * f0.x;
    a1 += ex * f0.y;
    a2 += ex * f1.x;
    a3 += ex * f1.y;
    den += ex;
  }
  float inv = 1.f / den;
  *(float4*)(out1 + (size_t)n * 128 + c4) = make_float4(a0 * inv, a1 * inv, a2 * inv, a3 * inv);
}

// -------------------- layer-2 GEMM: hl(fp16) = elu(out1+bias1) @ W2, plus logits --------
__global__ __launch_bounds__(64) void k_lin2(
    const float* __restrict__ out1, const float* __restrict__ bias1,
    const float* __restrict__ W2,
    const float* __restrict__ as2w, const float* __restrict__ ad2w,
    __half* __restrict__ hlh, float* __restrict__ asrc2, float* __restrict__ adst2) {
  const int n  = blockIdx.x * 64 + threadIdx.x;
  const int nc = n < NN ? n : NN - 1;
  const float4* xr = (const float4*)(out1 + (size_t)nc * 128);
  const float4* br = (const float4*)bias1;   // uniform
  float acc[32];
  #pragma unroll
  for (int j = 0; j < 32; ++j) acc[j] = 0.f;
  float4 xv = xr[0];
  for (int kt = 0; kt < 32; ++kt) {
    float4 cur = xv;
    if (kt < 31) xv = xr[kt + 1];
    float4 b = br[kt];                       // uniform
    cur.x += b.x; cur.y += b.y; cur.z += b.z; cur.w += b.w;
    cur.x = cur.x > 0.f ? cur.x : (expf(cur.x) - 1.f);   // ELU (once per element)
    cur.y = cur.y > 0.f ? cur.y : (expf(cur.y) - 1.f);
    cur.z = cur.z > 0.f ? cur.z : (expf(cur.z) - 1.f);
    cur.w = cur.w > 0.f ? cur.w : (expf(cur.w) - 1.f);
    GEMM_STEP(W2, (kt * 4 + 0) * 32, cur.x);
    GEMM_STEP(W2, (kt * 4 + 1) * 32, cur.y);
    GEMM_STEP(W2, (kt * 4 + 2) * 32, cur.z);
    GEMM_STEP(W2, (kt * 4 + 3) * 32, cur.w);
  }
  if (n < NN) {
    __align__(16) __half hbuf[32];
    #pragma unroll
    for (int j = 0; j < 32; ++j) hbuf[j] = __float2half_rn(acc[j]);
    float4* dst = (float4*)(hlh + (size_t)n * 32);   // 64 B
    #pragma unroll
    for (int i = 0; i < 4; ++i) dst[i] = ((const float4*)hbuf)[i];
    float ps = 0.f, pd = 0.f;
    #pragma unroll
    for (int j = 0; j < 32; ++j) {
      ps += acc[j] * as2w[j];                // uniform
      pd += acc[j] * ad2w[j];
    }
    asrc2[n] = ps;
    adst2[n] = pd;
  }
}

// -------------------- layer-2 aggregation (fused softmax): 8 lanes/node, fused bias2 -----
__global__ __launch_bounds__(256) void k_agg2(
    const int* __restrict__ rowptr, const int* __restrict__ csr_src,
    const float* __restrict__ ea_slot, const float* __restrict__ asrc2,
    const float* __restrict__ adst2, const float* __restrict__ coef,
    const __half* __restrict__ hlh, const float* __restrict__ bias2,
    float* __restrict__ out) {
  int n = blockIdx.x * 32 + (threadIdx.x >> 3);
  if (n >= NN) return;
  int c4 = (threadIdx.x & 7) << 2;
  float cf = coef[4];
  float ad = adst2[n];
  int r0 = rowptr[n], r1 = rowptr[n + 1];
  float a0 = 0.f, a1 = 0.f, a2 = 0.f, a3 = 0.f, den = 0.f;
  int s = csr_src[r0];
  float ea = ea_slot[r0];
  float as = asrc2[s];
  for (int j = r0; j < r1; ++j) {
    int sc = s; float eac = ea; float asc = as;
    if (j + 1 < r1) {
      s = csr_src[j + 1];
      ea = ea_slot[j + 1];
      as = asrc2[s];
    }
    uint2 raw = *(const uint2*)(hlh + (size_t)sc * 32 + c4);   // 4 halfs
    float alpha = asc + ad + eac * cf;
    alpha = alpha > 0.f ? alpha : NEG * alpha;
    float ex = __expf(alpha);
    __half2 p0, p1;
    *(unsigned int*)&p0 = raw.x;
    *(unsigned int*)&p1 = raw.y;
    float2 f0 = __half22float2(p0), f1 = __half22float2(p1);
    a0 += ex * f0.x;
    a1 += ex * f0.y;
    a2 += ex * f1.x;
    a3 += ex * f1.y;
    den += ex;
  }
  float inv = 1.f / den;
  float4 b = *(const float4*)(bias2 + c4);
  *(float4*)(out + (size_t)n * 32 + c4) =
      make_float4(a0 * inv + b.x, a1 * inv + b.y, a2 * inv + b.z, a3 * inv + b.w);
}

extern "C" void kernel_launch(void* const* d_in, const int* in_sizes, int n_in,
                              void* d_out, int out_size, void* d_ws, size_t ws_size,
                              hipStream_t stream) {
  const float* x        = (const float*)d_in[0];
  const int*   ei       = (const int*)d_in[1];
  const float* eattr    = (const float*)d_in[2];
  const float* lin1_w   = (const float*)d_in[3];
  const float* att1_src = (const float*)d_in[4];
  const float* att1_dst = (const float*)d_in[5];
  const float* lin1_ew  = (const float*)d_in[6];
  const float* att1_e   = (const float*)d_in[7];
  // bias1 = d_in[8]
  const float* lin2_w   = (const float*)d_in[9];
  const float* att2_src = (const float*)d_in[10];
  const float* att2_dst = (const float*)d_in[11];
  const float* lin2_ew  = (const float*)d_in[12];
  const float* att2_e   = (const float*)d_in[13];
  const float* bias1    = (const float*)d_in[8];
  const float* bias2    = (const float*)d_in[14];
  float* out = (float*)d_out;
  float* ws  = (float*)d_ws;
  int*   wsi = (int*)d_ws;

  int*    deg     = wsi + O_DEG;
  float*  easum   = ws + O_EASUM;
  float*  coef    = ws + O_COEF;
  int*    rowptr  = wsi + O_ROWPTR;
  int*    cursor  = wsi + O_CURSOR;
  int*    blksum  = wsi + O_BLKSUM;
  int*    blkoff  = wsi + O_BLKOFF;
  int*    csr_src = wsi + O_CSRSRC;
  float*  ea_slot = ws + O_EASLOT;
  float*  asrc1   = ws + O_ASRC1;
  float*  adst1   = ws + O_ADST1;
  __half* xlh     = (__half*)(ws + O_XLH);
  float*  out1    = ws + O_OUT1;
  __half* hlh     = (__half*)(ws + O_HLH);
  float*  asrc2   = ws + O_ASRC2;
  float*  adst2   = ws + O_ADST2;

  // zero deg/easum (ws poisoned 0xAA each call)
  hipMemsetAsync(ws, 0, (size_t)ZERO_ELEMS * sizeof(float), stream);

  k_ea_count<<<256, 256, 0, stream>>>(eattr, ei, easum, deg);
  k_coef<<<1, 128, 0, stream>>>(lin1_ew, att1_e, lin2_ew, att2_e, coef);

  // CSR build (dst-sorted): multi-block scan
  k_scan_blk<<<SCAN_BLOCKS, 256, 0, stream>>>(deg, rowptr, blksum);
  k_scan_top<<<1, 256, 0, stream>>>(blksum, blkoff);
  k_scan_add<<<SCAN_BLOCKS, 256, 0, stream>>>(rowptr, cursor, blkoff);
  k_fill<<<(ETOT + 255) / 256, 256, 0, stream>>>(ei, eattr, easum, cursor, csr_src, ea_slot);

  // layer 1
  k_lin1<<<L1_NB * 4, 64, 0, stream>>>(x, lin1_w, att1_src, att1_dst, xlh, asrc1, adst1);
  k_agg1<<<(NN + 7) / 8, 256, 0, stream>>>(rowptr, csr_src, ea_slot, asrc1, adst1, coef, xlh, out1);

  // layer 2
  k_lin2<<<(NN + 63) / 64, 64, 0, stream>>>(out1, bias1, lin2_w, att2_src, att2_dst, hlh, asrc2, adst2);
  k_agg2<<<(NN + 31) / 32, 256, 0, stream>>>(rowptr, csr_src, ea_slot, asrc2, adst2, coef, hlh, bias2, out);
}

// Round 7
// 312.731 us; speedup vs baseline: 7.2324x; 1.1084x over previous
//
#include <hip/hip_runtime.h>
#include <hip/hip_fp16.h>
#include <math.h>

// GAT 2-layer, N=50000, E=800000 (+N self loops), IN=128, HID=32, HEADS=4, OUT=32
#define NN   50000
#define EE   800000
#define ETOT 850000          // EE + NN
#define NEG  0.2f
#define SCAN_BLOCKS ((NN + 255) / 256)   // 196

// -------- workspace layout (element offsets, 4B units; ints/halfs alias floats) --------
// zero-initialized region (one contiguous memset):
#define O_DEG    0           //    50,000  in-degree per node (int, EXCLUDING self-loop)
#define O_EASUM  50000       //         4  edge_attr sum (scalar)
#define ZERO_ELEMS 50004
// non-zeroed:
#define O_COEF   50004       //         8  coef1[4], coef2 at [4]
#define O_ROWPTR 50012       //    50,001  CSR row pointers (int)
#define O_CURSOR 100016      //    50,000  fill cursors (int)
#define O_BLKSUM 150016      //       256  per-block scan totals (int)
#define O_BLKOFF 150272      //       256  per-block scan offsets (int)
#define O_CSRSRC 150528      //   850,000  src node per CSR slot (int)
#define O_EASLOT 1000528     //   850,000  edge attr in CSR slot order (float)
#define O_ASRC1  1850528     //   200,000  per-node src logits layer1 [N][4]
#define O_ADST1  2050528     //   200,000  per-node dst logits layer1 [N][4]
#define O_XLH    2250528     // 3,200,000  layer-1 features fp16 [N][128] (6.4M halfs)
#define O_OUT1   5450528     // 6,400,000  layer-1 agg output fp32 [N][128]
#define O_HLH    11850528    //   800,000  layer-2 features fp16 [N][32] (1.6M halfs)
#define O_ASRC2  12650528    //    50,000  per-node src logits layer2
#define O_ADST2  12700528    //    50,000  per-node dst logits layer2
#define WS_ELEMS 12750528    // ~51 MB

// -------------------- fused: edge_attr sum + degree count (real edges only) -----------
__global__ void k_ea_count(const float* __restrict__ ea, const int* __restrict__ ei,
                           float* __restrict__ easum, int* __restrict__ deg) {
  __shared__ float red[4];
  float s = 0.f;
  int stride = gridDim.x * blockDim.x;
  for (int i = blockIdx.x * blockDim.x + threadIdx.x; i < EE; i += stride) {
    s += ea[i];
    atomicAdd(deg + ei[EE + i], 1);
  }
  #pragma unroll
  for (int o = 32; o > 0; o >>= 1) s += __shfl_down(s, o, 64);
  if ((threadIdx.x & 63) == 0) red[threadIdx.x >> 6] = s;
  __syncthreads();
  if (threadIdx.x == 0) atomicAdd(easum, red[0] + red[1] + red[2] + red[3]);
}

// -------------------- edge-coef precompute --------------------
__global__ void k_coef(const float* __restrict__ lew1, const float* __restrict__ ae1,
                       const float* __restrict__ lew2, const float* __restrict__ ae2,
                       float* __restrict__ coef) {
  int t = threadIdx.x; // 128 threads
  float p = lew1[t] * ae1[t];
  #pragma unroll
  for (int o = 16; o > 0; o >>= 1) p += __shfl_down(p, o, 32);
  if ((t & 31) == 0) coef[t >> 5] = p;
  if (t < 32) {
    float q = lew2[t] * ae2[t];
    #pragma unroll
    for (int o = 16; o > 0; o >>= 1) q += __shfl_down(q, o, 32);
    if (t == 0) coef[4] = q;
  }
}

// -------------------- multi-block exclusive scan of (deg+1) --------------------
__device__ __forceinline__ int wave_incl_scan(int v, int lane) {
  #pragma unroll
  for (int o = 1; o < 64; o <<= 1) {
    int u = __shfl_up(v, o, 64);
    if (lane >= o) v += u;
  }
  return v;
}

__global__ __launch_bounds__(256) void k_scan_blk(const int* __restrict__ deg,
                                                  int* __restrict__ rowptr,
                                                  int* __restrict__ blksum) {
  __shared__ int wsum[4];
  const int t = threadIdx.x;
  const int i = blockIdx.x * 256 + t;
  const int lane = t & 63, wv = t >> 6;
  int v = (i < NN) ? (deg[i] + 1) : 0;       // +1 = self-loop
  int incl = wave_incl_scan(v, lane);
  if (lane == 63) wsum[wv] = incl;
  __syncthreads();
  int off = 0;
  #pragma unroll
  for (int k = 0; k < 4; ++k) if (k < wv) off += wsum[k];
  incl += off;
  if (i < NN) rowptr[i] = incl - v;          // local exclusive
  if (t == 255) blksum[blockIdx.x] = incl;   // block total
}

__global__ __launch_bounds__(256) void k_scan_top(const int* __restrict__ blksum,
                                                  int* __restrict__ blkoff) {
  __shared__ int wsum[4];
  const int t = threadIdx.x;
  const int lane = t & 63, wv = t >> 6;
  int v = (t < SCAN_BLOCKS) ? blksum[t] : 0;
  int incl = wave_incl_scan(v, lane);
  if (lane == 63) wsum[wv] = incl;
  __syncthreads();
  int off = 0;
  #pragma unroll
  for (int k = 0; k < 4; ++k) if (k < wv) off += wsum[k];
  incl += off;
  if (t < SCAN_BLOCKS) blkoff[t] = incl - v;
}

__global__ __launch_bounds__(256) void k_scan_add(int* __restrict__ rowptr,
                                                  int* __restrict__ cursor,
                                                  const int* __restrict__ blkoff) {
  const int i = blockIdx.x * 256 + threadIdx.x;
  if (i < NN) {
    int r = rowptr[i] + blkoff[blockIdx.x];
    rowptr[i] = r;
    cursor[i] = r;
  }
  if (i == 0) rowptr[NN] = ETOT;
}

// fill CSR src + edge attr in slot order (self-loop attr = mean)
__global__ void k_fill(const int* __restrict__ ei, const float* __restrict__ eattr,
                       const float* __restrict__ easum, int* __restrict__ cursor,
                       int* __restrict__ csr_src, float* __restrict__ ea_slot) {
  int e = blockIdx.x * 256 + threadIdx.x;
  if (e >= ETOT) return;
  int s, d; float ea;
  if (e < EE) { s = ei[e]; d = ei[EE + e]; ea = eattr[e]; }
  else { s = d = e - EE; ea = easum[0] * (1.f / EE); }
  int slot = atomicAdd(cursor + d, 1);
  csr_src[slot] = s;
  ea_slot[slot] = ea;
}

// 32 FMAs against one uniform W row of 32 floats
#define GEMM_STEP(WB, K, XS) {                                              \
    const float4* Wr = (const float4*)((WB) + (size_t)(K));                 \
    _Pragma("unroll")                                                       \
    for (int j4 = 0; j4 < 8; ++j4) {                                        \
      float4 wv = Wr[j4];                                                   \
      acc[j4 * 4 + 0] += (XS) * wv.x;                                       \
      acc[j4 * 4 + 1] += (XS) * wv.y;                                       \
      acc[j4 * 4 + 2] += (XS) * wv.z;                                       \
      acc[j4 * 4 + 3] += (XS) * wv.w;                                       \
    } }

// -------------------- layer-1 GEMM: xl(fp16) = x @ W1, plus per-node logits -------------
// 1 wave per block; head varies SLOWEST across grid (x re-reads hit L3);
// lane = node; wave-uniform W -> scalar loads; NO LDS, no barriers.
#define L1_NB ((NN + 63) / 64)      // 782 node-blocks per head
__global__ __launch_bounds__(64) void k_lin1(
    const float* __restrict__ x, const float* __restrict__ W,
    const float* __restrict__ att_src, const float* __restrict__ att_dst,
    __half* __restrict__ xlh, float* __restrict__ asrc, float* __restrict__ adst) {
  const int bid = blockIdx.x;
  const int h   = bid / L1_NB;                // head (uniform, slowest)
  const int n   = (bid % L1_NB) * 64 + threadIdx.x;
  const int nc  = n < NN ? n : NN - 1;
  const float4* xr = (const float4*)(x + (size_t)nc * 128);
  const float*  Wh = W + h * 32;              // uniform base
  float acc[32];
  #pragma unroll
  for (int j = 0; j < 32; ++j) acc[j] = 0.f;
  float4 xv = xr[0];
  for (int kt = 0; kt < 32; ++kt) {
    float4 cur = xv;
    if (kt < 31) xv = xr[kt + 1];             // prefetch next 16B of x
    GEMM_STEP(Wh, (kt * 4 + 0) * 128, cur.x);
    GEMM_STEP(Wh, (kt * 4 + 1) * 128, cur.y);
    GEMM_STEP(Wh, (kt * 4 + 2) * 128, cur.z);
    GEMM_STEP(Wh, (kt * 4 + 3) * 128, cur.w);
  }
  if (n < NN) {
    __align__(16) __half hbuf[32];
    #pragma unroll
    for (int j = 0; j < 32; ++j) hbuf[j] = __float2half_rn(acc[j]);
    float4* dst = (float4*)(xlh + (size_t)n * 128 + h * 32);   // 64 B, 16B-aligned
    #pragma unroll
    for (int i = 0; i < 4; ++i) dst[i] = ((const float4*)hbuf)[i];
    float ss = 0.f, sd = 0.f;
    #pragma unroll
    for (int j = 0; j < 32; ++j) {
      ss += acc[j] * att_src[h * 32 + j];     // uniform
      sd += acc[j] * att_dst[h * 32 + j];
    }
    asrc[n * 4 + h] = ss;
    adst[n * 4 + h] = sd;
  }
}

// -------------------- layer-1 aggregation (fused softmax), batch-4 pipelined ------------
// half-wave per node, lane = 4 channels; per batch: 4 slot loads -> 4 indep
// metadata loads + 4 indep row gathers -> math. Tail masked branch-free.
__global__ __launch_bounds__(256) void k_agg1(
    const int* __restrict__ rowptr, const int* __restrict__ csr_src,
    const float* __restrict__ ea_slot, const float* __restrict__ asrc,
    const float* __restrict__ adst, const float* __restrict__ coef,
    const __half* __restrict__ xlh, float* __restrict__ out1) {
  int n = blockIdx.x * 8 + (threadIdx.x >> 5);
  if (n >= NN) return;
  int l = threadIdx.x & 31;
  int c4 = l << 2;                    // 4 channels per lane, 32 lanes = 128 ch
  int h = l >> 3;                     // head of this channel group
  float cf = coef[h];
  float ad = adst[(size_t)n * 4 + h];
  int r0 = rowptr[n], r1 = rowptr[n + 1];   // r1 > r0 (self-loop)
  float a0 = 0.f, a1 = 0.f, a2 = 0.f, a3 = 0.f, den = 0.f;
  for (int j = r0; j < r1; j += 4) {
    int sv[4]; float eav[4], asv[4]; uint2 raw[4];
    #pragma unroll
    for (int k = 0; k < 4; ++k) {
      int jj = (j + k < r1) ? (j + k) : (r1 - 1);
      sv[k] = csr_src[jj];
      eav[k] = ea_slot[jj];
    }
    #pragma unroll
    for (int k = 0; k < 4; ++k) {
      asv[k] = asrc[(size_t)sv[k] * 4 + h];
      raw[k] = *(const uint2*)(xlh + (size_t)sv[k] * 128 + c4);   // 4 halfs
    }
    #pragma unroll
    for (int k = 0; k < 4; ++k) {
      float alpha = asv[k] + ad + eav[k] * cf;
      alpha = alpha > 0.f ? alpha : NEG * alpha;
      float ex = (j + k < r1) ? __expf(alpha) : 0.f;   // tail mask
      __half2 p0, p1;
      *(unsigned int*)&p0 = raw[k].x;
      *(unsigned int*)&p1 = raw[k].y;
      float2 f0 = __half22float2(p0), f1 = __half22float2(p1);
      a0 += ex * f0.x;
      a1 += ex * f0.y;
      a2 += ex * f1.x;
      a3 += ex * f1.y;
      den += ex;
    }
  }
  float inv = 1.f / den;
  *(float4*)(out1 + (size_t)n * 128 + c4) = make_float4(a0 * inv, a1 * inv, a2 * inv, a3 * inv);
}

// -------------------- layer-2 GEMM: hl(fp16) = elu(out1+bias1) @ W2, plus logits --------
__global__ __launch_bounds__(64) void k_lin2(
    const float* __restrict__ out1, const float* __restrict__ bias1,
    const float* __restrict__ W2,
    const float* __restrict__ as2w, const float* __restrict__ ad2w,
    __half* __restrict__ hlh, float* __restrict__ asrc2, float* __restrict__ adst2) {
  const int n  = blockIdx.x * 64 + threadIdx.x;
  const int nc = n < NN ? n : NN - 1;
  const float4* xr = (const float4*)(out1 + (size_t)nc * 128);
  const float4* br = (const float4*)bias1;   // uniform
  float acc[32];
  #pragma unroll
  for (int j = 0; j < 32; ++j) acc[j] = 0.f;
  float4 xv = xr[0];
  for (int kt = 0; kt < 32; ++kt) {
    float4 cur = xv;
    if (kt < 31) xv = xr[kt + 1];
    float4 b = br[kt];                       // uniform
    cur.x += b.x; cur.y += b.y; cur.z += b.z; cur.w += b.w;
    cur.x = cur.x > 0.f ? cur.x : (expf(cur.x) - 1.f);   // ELU (once per element)
    cur.y = cur.y > 0.f ? cur.y : (expf(cur.y) - 1.f);
    cur.z = cur.z > 0.f ? cur.z : (expf(cur.z) - 1.f);
    cur.w = cur.w > 0.f ? cur.w : (expf(cur.w) - 1.f);
    GEMM_STEP(W2, (kt * 4 + 0) * 32, cur.x);
    GEMM_STEP(W2, (kt * 4 + 1) * 32, cur.y);
    GEMM_STEP(W2, (kt * 4 + 2) * 32, cur.z);
    GEMM_STEP(W2, (kt * 4 + 3) * 32, cur.w);
  }
  if (n < NN) {
    __align__(16) __half hbuf[32];
    #pragma unroll
    for (int j = 0; j < 32; ++j) hbuf[j] = __float2half_rn(acc[j]);
    float4* dst = (float4*)(hlh + (size_t)n * 32);   // 64 B
    #pragma unroll
    for (int i = 0; i < 4; ++i) dst[i] = ((const float4*)hbuf)[i];
    float ps = 0.f, pd = 0.f;
    #pragma unroll
    for (int j = 0; j < 32; ++j) {
      ps += acc[j] * as2w[j];                // uniform
      pd += acc[j] * ad2w[j];
    }
    asrc2[n] = ps;
    adst2[n] = pd;
  }
}

// -------------------- layer-2 aggregation (fused softmax), batch-4 pipelined ------------
__global__ __launch_bounds__(256) void k_agg2(
    const int* __restrict__ rowptr, const int* __restrict__ csr_src,
    const float* __restrict__ ea_slot, const float* __restrict__ asrc2,
    const float* __restrict__ adst2, const float* __restrict__ coef,
    const __half* __restrict__ hlh, const float* __restrict__ bias2,
    float* __restrict__ out) {
  int n = blockIdx.x * 32 + (threadIdx.x >> 3);
  if (n >= NN) return;
  int c4 = (threadIdx.x & 7) << 2;
  float cf = coef[4];
  float ad = adst2[n];
  int r0 = rowptr[n], r1 = rowptr[n + 1];
  float a0 = 0.f, a1 = 0.f, a2 = 0.f, a3 = 0.f, den = 0.f;
  for (int j = r0; j < r1; j += 4) {
    int sv[4]; float eav[4], asv[4]; uint2 raw[4];
    #pragma unroll
    for (int k = 0; k < 4; ++k) {
      int jj = (j + k < r1) ? (j + k) : (r1 - 1);
      sv[k] = csr_src[jj];
      eav[k] = ea_slot[jj];
    }
    #pragma unroll
    for (int k = 0; k < 4; ++k) {
      asv[k] = asrc2[sv[k]];
      raw[k] = *(const uint2*)(hlh + (size_t)sv[k] * 32 + c4);   // 4 halfs
    }
    #pragma unroll
    for (int k = 0; k < 4; ++k) {
      float alpha = asv[k] + ad + eav[k] * cf;
      alpha = alpha > 0.f ? alpha : NEG * alpha;
      float ex = (j + k < r1) ? __expf(alpha) : 0.f;   // tail mask
      __half2 p0, p1;
      *(unsigned int*)&p0 = raw[k].x;
      *(unsigned int*)&p1 = raw[k].y;
      float2 f0 = __half22float2(p0), f1 = __half22float2(p1);
      a0 += ex * f0.x;
      a1 += ex * f0.y;
      a2 += ex * f1.x;
      a3 += ex * f1.y;
      den += ex;
    }
  }
  float inv = 1.f / den;
  float4 b = *(const float4*)(bias2 + c4);
  *(float4*)(out + (size_t)n * 32 + c4) =
      make_float4(a0 * inv + b.x, a1 * inv + b.y, a2 * inv + b.z, a3 * inv + b.w);
}

extern "C" void kernel_launch(void* const* d_in, const int* in_sizes, int n_in,
                              void* d_out, int out_size, void* d_ws, size_t ws_size,
                              hipStream_t stream) {
  const float* x        = (const float*)d_in[0];
  const int*   ei       = (const int*)d_in[1];
  const float* eattr    = (const float*)d_in[2];
  const float* lin1_w   = (const float*)d_in[3];
  const float* att1_src = (const float*)d_in[4];
  const float* att1_dst = (const float*)d_in[5];
  const float* lin1_ew  = (const float*)d_in[6];
  const float* att1_e   = (const float*)d_in[7];
  const float* bias1    = (const float*)d_in[8];
  const float* lin2_w   = (const float*)d_in[9];
  const float* att2_src = (const float*)d_in[10];
  const float* att2_dst = (const float*)d_in[11];
  const float* lin2_ew  = (const float*)d_in[12];
  const float* att2_e   = (const float*)d_in[13];
  const float* bias2    = (const float*)d_in[14];
  float* out = (float*)d_out;
  float* ws  = (float*)d_ws;
  int*   wsi = (int*)d_ws;

  int*    deg     = wsi + O_DEG;
  float*  easum   = ws + O_EASUM;
  float*  coef    = ws + O_COEF;
  int*    rowptr  = wsi + O_ROWPTR;
  int*    cursor  = wsi + O_CURSOR;
  int*    blksum  = wsi + O_BLKSUM;
  int*    blkoff  = wsi + O_BLKOFF;
  int*    csr_src = wsi + O_CSRSRC;
  float*  ea_slot = ws + O_EASLOT;
  float*  asrc1   = ws + O_ASRC1;
  float*  adst1   = ws + O_ADST1;
  __half* xlh     = (__half*)(ws + O_XLH);
  float*  out1    = ws + O_OUT1;
  __half* hlh     = (__half*)(ws + O_HLH);
  float*  asrc2   = ws + O_ASRC2;
  float*  adst2   = ws + O_ADST2;

  // zero deg/easum (ws poisoned 0xAA each call)
  hipMemsetAsync(ws, 0, (size_t)ZERO_ELEMS * sizeof(float), stream);

  k_ea_count<<<256, 256, 0, stream>>>(eattr, ei, easum, deg);
  k_coef<<<1, 128, 0, stream>>>(lin1_ew, att1_e, lin2_ew, att2_e, coef);

  // CSR build (dst-sorted): multi-block scan
  k_scan_blk<<<SCAN_BLOCKS, 256, 0, stream>>>(deg, rowptr, blksum);
  k_scan_top<<<1, 256, 0, stream>>>(blksum, blkoff);
  k_scan_add<<<SCAN_BLOCKS, 256, 0, stream>>>(rowptr, cursor, blkoff);
  k_fill<<<(ETOT + 255) / 256, 256, 0, stream>>>(ei, eattr, easum, cursor, csr_src, ea_slot);

  // layer 1
  k_lin1<<<L1_NB * 4, 64, 0, stream>>>(x, lin1_w, att1_src, att1_dst, xlh, asrc1, adst1);
  k_agg1<<<(NN + 7) / 8, 256, 0, stream>>>(rowptr, csr_src, ea_slot, asrc1, adst1, coef, xlh, out1);

  // layer 2
  k_lin2<<<(NN + 63) / 64, 64, 0, stream>>>(out1, bias1, lin2_w, att2_src, att2_dst, hlh, asrc2, adst2);
  k_agg2<<<(NN + 31) / 32, 256, 0, stream>>>(rowptr, csr_src, ea_slot, asrc2, adst2, coef, hlh, bias2, out);
}